// Round 1
// baseline (819.743 us; speedup 1.0000x reference)
//
#include <hip/hip_runtime.h>
#include <hip/hip_bf16.h>
#include <math.h>

typedef __bf16 bf16_t;
typedef __bf16 bf16x8 __attribute__((ext_vector_type(8)));
typedef float  f32x4  __attribute__((ext_vector_type(4)));

#define BB 4096
#define NN 2048
#define DD 1024
#define HH 4096
#define KSEL 5
#define NHEAD 8

__device__ __forceinline__ unsigned short bfbits(float f) {
  return __builtin_bit_cast(unsigned short, (bf16_t)f);
}

__device__ __forceinline__ void gload_lds16(const void* g, void* l) {
  __builtin_amdgcn_global_load_lds(
      (const __attribute__((address_space(1))) void*)g,
      (__attribute__((address_space(3))) void*)l, 16, 0, 0);
}

// ---------------- elementwise prep ----------------
__global__ void f2b_k(const float4* __restrict__ in, ushort4* __restrict__ out, int n4) {
  int i = blockIdx.x * 256 + threadIdx.x;
  if (i >= n4) return;
  float4 x = in[i];
  ushort4 o;
  o.x = bfbits(x.x); o.y = bfbits(x.y); o.z = bfbits(x.z); o.w = bfbits(x.w);
  out[i] = o;
}

__global__ void evo_k(const float4* __restrict__ a, const float4* __restrict__ b,
                      ushort4* __restrict__ out, int n4) {
  int i = blockIdx.x * 256 + threadIdx.x;
  if (i >= n4) return;
  float4 x = a[i], y = b[i];
  ushort4 o;
  o.x = bfbits(y.x - x.x); o.y = bfbits(y.y - x.y);
  o.z = bfbits(y.z - x.z); o.w = bfbits(y.w - x.w);
  out[i] = o;
}

// 1/||stored_morph0_n|| in fp64 (used by approx top-k scale and fp64 refine)
__global__ void rnormd_k(const float* __restrict__ s0, double* __restrict__ rnd) {
  __shared__ double red[256];
  int n = blockIdx.x, tid = threadIdx.x;
  const float4* row = (const float4*)(s0 + (size_t)n * DD);
  float4 x = row[tid];
  double ss = (double)x.x * x.x + (double)x.y * x.y + (double)x.z * x.z + (double)x.w * x.w;
  red[tid] = ss; __syncthreads();
  for (int s = 128; s > 0; s >>= 1) {
    if (tid < s) red[tid] += red[tid + s];
    __syncthreads();
  }
  if (tid == 0) rnd[n] = 1.0 / fmax(sqrt(red[0]), 1e-12);
}

// ---------------- bf16 MFMA GEMM: C[M,Nn] = epi(A[M,Kk] @ Bw[Nn,Kk]^T) ----------------
template<bool GATHER, bool RELU, bool RESID, bool OUTBF16>
__global__ void __launch_bounds__(256)
gemm_bt(const bf16_t* __restrict__ A, const bf16_t* __restrict__ Bw,
        const float* __restrict__ bias, const float* __restrict__ resid,
        const int* __restrict__ gidx,
        float* __restrict__ outf, bf16_t* __restrict__ outb,
        int M, int Nn, int Kk)
{
  __shared__ alignas(16) bf16_t At[4096];   // [128 rows][32 k] bf16
  __shared__ alignas(16) bf16_t Bt[4096];
  const int tid = threadIdx.x;
  const int wave = tid >> 6, lane = tid & 63;
  const int wm = wave >> 1, wn = wave & 1;
  const int bm = blockIdx.y << 7, bn = blockIdx.x << 7;

  // staging: flat byte off = tid*16 + r*4096 ; row = off>>6 ; colbyte = off&63
  const int srow  = (wave << 4) + (lane >> 2);   // 0..63
  const int scolb = (lane & 3) << 4;             // 0,16,32,48
  int ar0 = bm + srow, ar1 = bm + srow + 64;
  if (GATHER) { ar0 = gidx[ar0]; ar1 = gidx[ar1]; }
  const char* pA0 = (const char*)A  + (size_t)ar0 * Kk * 2 + scolb;
  const char* pA1 = (const char*)A  + (size_t)ar1 * Kk * 2 + scolb;
  const char* pB0 = (const char*)Bw + (size_t)(bn + srow) * Kk * 2 + scolb;
  const char* pB1 = (const char*)Bw + (size_t)(bn + srow + 64) * Kk * 2 + scolb;
  char* lA = (char*)At + (wave << 10);
  char* lB = (char*)Bt + (wave << 10);

  f32x4 zero = {0.f, 0.f, 0.f, 0.f};
  f32x4 acc[4][4];
  #pragma unroll
  for (int i = 0; i < 4; ++i)
    #pragma unroll
    for (int j = 0; j < 4; ++j) acc[i][j] = zero;

  const bf16_t* fA = At + ((wm << 6) + (lane & 15)) * 32 + ((lane >> 4) << 3);
  const bf16_t* fB = Bt + ((wn << 6) + (lane & 15)) * 32 + ((lane >> 4) << 3);

  for (int k0 = 0; k0 < Kk; k0 += 32) {
    gload_lds16(pA0, lA);
    gload_lds16(pA1, lA + 4096);
    gload_lds16(pB0, lB);
    gload_lds16(pB1, lB + 4096);
    pA0 += 64; pA1 += 64; pB0 += 64; pB1 += 64;
    __syncthreads();
    bf16x8 av[4], bv[4];
    #pragma unroll
    for (int i = 0; i < 4; ++i) av[i] = *(const bf16x8*)(fA + i * 512);
    #pragma unroll
    for (int j = 0; j < 4; ++j) bv[j] = *(const bf16x8*)(fB + j * 512);
    #pragma unroll
    for (int i = 0; i < 4; ++i)
      #pragma unroll
      for (int j = 0; j < 4; ++j)
        acc[i][j] = __builtin_amdgcn_mfma_f32_16x16x32_bf16(av[i], bv[j], acc[i][j], 0, 0, 0);
    __syncthreads();
  }

  // C/D layout (m89-verified): col=lane&15, row=(lane>>4)*4+reg
  const int r0 = bm + (wm << 6) + ((lane >> 4) << 2);
  const int c0 = bn + (wn << 6) + (lane & 15);
  #pragma unroll
  for (int i = 0; i < 4; ++i) {
    #pragma unroll
    for (int j = 0; j < 4; ++j) {
      #pragma unroll
      for (int r = 0; r < 4; ++r) {
        int row = r0 + i * 16 + r;
        int col = c0 + j * 16;
        size_t o = (size_t)row * Nn + col;
        float v = acc[i][j][r];
        if (bias)  v += bias[col];
        if (RESID) v += resid[o];
        if (RELU)  v = fmaxf(v, 0.f);
        if (OUTBF16) outb[o] = (bf16_t)v;
        else         outf[o] = v;
      }
    }
  }
}

// ---------------- approx top-8 per row ----------------
__global__ void __launch_bounds__(256)
topk8_k(const float* __restrict__ sim, const double* __restrict__ rnd,
        int* __restrict__ cand)
{
  __shared__ float vals[NN];
  __shared__ float rv[256];
  __shared__ int   ri[256];
  int b = blockIdx.x, tid = threadIdx.x;
  for (int t = 0; t < NN / 256; ++t) {
    int i = tid + t * 256;
    vals[i] = sim[(size_t)b * NN + i] * (float)rnd[i];
  }
  __syncthreads();
  for (int p = 0; p < 8; ++p) {
    float bvv = -INFINITY; int bi = NN;
    for (int t = 0; t < NN / 256; ++t) {
      int i = tid + t * 256;
      float v = vals[i];
      if (v > bvv) { bvv = v; bi = i; }   // strict > keeps lowest index
    }
    rv[tid] = bvv; ri[tid] = bi;
    __syncthreads();
    for (int s = 128; s > 0; s >>= 1) {
      if (tid < s) {
        float v2 = rv[tid + s]; int i2 = ri[tid + s];
        if (v2 > rv[tid] || (v2 == rv[tid] && i2 < ri[tid])) { rv[tid] = v2; ri[tid] = i2; }
      }
      __syncthreads();
    }
    if (tid == 0) {
      int wsel = ri[0];
      cand[b * 8 + p] = wsel;
      vals[wsel] = -INFINITY;
    }
    __syncthreads();
  }
}

// ---------------- fp64 re-rank of the 8 candidates -> exact top-5 ----------------
__global__ void __launch_bounds__(256)
refine_k(const float* __restrict__ m0, const float* __restrict__ s0,
         const double* __restrict__ rnd, const int* __restrict__ cand,
         int* __restrict__ topidx)
{
  __shared__ double red[256];
  __shared__ double vals[8];
  int b = blockIdx.x, tid = threadIdx.x;
  int cs[8];
  #pragma unroll
  for (int j = 0; j < 8; ++j) cs[j] = cand[b * 8 + j];
  const float* q = m0 + (size_t)b * DD;
  double part[8];
  #pragma unroll
  for (int j = 0; j < 8; ++j) part[j] = 0.0;
  for (int d = tid; d < DD; d += 256) {
    double qd = (double)q[d];
    #pragma unroll
    for (int j = 0; j < 8; ++j)
      part[j] += qd * (double)s0[(size_t)cs[j] * DD + d];
  }
  for (int j = 0; j < 8; ++j) {
    red[tid] = part[j]; __syncthreads();
    for (int s = 128; s > 0; s >>= 1) {
      if (tid < s) red[tid] += red[tid + s];
      __syncthreads();
    }
    if (tid == 0) vals[j] = red[0] * rnd[cs[j]];
    __syncthreads();
  }
  if (tid == 0) {
    bool used[8] = {false,false,false,false,false,false,false,false};
    for (int p = 0; p < KSEL; ++p) {
      int best = -1;
      for (int j = 0; j < 8; ++j) {
        if (used[j]) continue;
        if (best < 0 || vals[j] > vals[best] ||
            (vals[j] == vals[best] && cs[j] < cs[best])) best = j;
      }
      used[best] = true;
      topidx[b * KSEL + p] = cs[best];
    }
  }
}

// ---------------- tiny attention: 1 block per b, 1 wave per head ----------------
__global__ void __launch_bounds__(512)
attn_k(const bf16_t* __restrict__ q, const bf16_t* __restrict__ kk,
       const bf16_t* __restrict__ vv, bf16_t* __restrict__ ctx,
       float* __restrict__ attn_out)
{
  __shared__ float aw[NHEAD][KSEL];
  int b = blockIdx.x;
  int h = threadIdx.x >> 6, lane = threadIdx.x & 63;
  size_t qoff = (size_t)b * DD + h * 128;
  float q0 = (float)q[qoff + lane], q1 = (float)q[qoff + lane + 64];
  float s[KSEL];
  #pragma unroll
  for (int j = 0; j < KSEL; ++j) {
    size_t ko = (size_t)(b * KSEL + j) * DD + h * 128;
    float p = q0 * (float)kk[ko + lane] + q1 * (float)kk[ko + lane + 64];
    #pragma unroll
    for (int m = 32; m > 0; m >>= 1) p += __shfl_xor(p, m);
    s[j] = p * 0.08838834764831845f;  // 1/sqrt(128)
  }
  float mx = s[0];
  #pragma unroll
  for (int j = 1; j < KSEL; ++j) mx = fmaxf(mx, s[j]);
  float e[KSEL], sum = 0.f;
  #pragma unroll
  for (int j = 0; j < KSEL; ++j) { e[j] = expf(s[j] - mx); sum += e[j]; }
  float inv = 1.f / sum;
  float o0 = 0.f, o1 = 0.f;
  #pragma unroll
  for (int j = 0; j < KSEL; ++j) {
    float a = e[j] * inv;
    size_t vo = (size_t)(b * KSEL + j) * DD + h * 128;
    o0 += a * (float)vv[vo + lane];
    o1 += a * (float)vv[vo + lane + 64];
    if (lane == 0) aw[h][j] = a;
  }
  ctx[qoff + lane]      = (bf16_t)o0;
  ctx[qoff + lane + 64] = (bf16_t)o1;
  __syncthreads();
  if (threadIdx.x < KSEL) {
    float m = 0.f;
    #pragma unroll
    for (int hh = 0; hh < NHEAD; ++hh) m += aw[hh][threadIdx.x];
    attn_out[(size_t)b * KSEL + threadIdx.x] = m * 0.125f;
  }
}

// ---------------- launch ----------------
extern "C" void kernel_launch(void* const* d_in, const int* in_sizes, int n_in,
                              void* d_out, int out_size, void* d_ws, size_t ws_size,
                              hipStream_t stream) {
  (void)in_sizes; (void)n_in; (void)out_size; (void)ws_size;
  const float* morph0 = (const float*)d_in[0];
  const float* s0     = (const float*)d_in[1];
  const float* s1     = (const float*)d_in[2];
  const float* wq = (const float*)d_in[3];  const float* bq = (const float*)d_in[4];
  const float* wk = (const float*)d_in[5];  const float* bk = (const float*)d_in[6];
  const float* wv = (const float*)d_in[7];  const float* bv = (const float*)d_in[8];
  const float* wo = (const float*)d_in[9];  const float* bo = (const float*)d_in[10];
  const float* w1 = (const float*)d_in[11]; const float* b1 = (const float*)d_in[12];
  const float* w2 = (const float*)d_in[13]; const float* b2 = (const float*)d_in[14];
  const float* w3 = (const float*)d_in[15]; const float* b3 = (const float*)d_in[16];

  char* ws = (char*)d_ws;
  size_t off = 0;
  auto alloc = [&](size_t bytes) { char* p = ws + off; off += (bytes + 255) & ~(size_t)255; return p; };

  float*  sim  = (float*) alloc((size_t)BB * NN * 4);          // reused as h1 (bf16) later
  bf16_t* m0b  = (bf16_t*)alloc((size_t)BB * DD * 2);
  bf16_t* s0b  = (bf16_t*)alloc((size_t)NN * DD * 2);
  bf16_t* evo  = (bf16_t*)alloc((size_t)NN * DD * 2);
  double* rnd  = (double*)alloc((size_t)NN * 8);
  int*    cand = (int*)   alloc((size_t)BB * 8 * 4);
  int*    tidx = (int*)   alloc((size_t)BB * KSEL * 4);
  bf16_t* qb   = (bf16_t*)alloc((size_t)BB * DD * 2);
  bf16_t* kb   = (bf16_t*)alloc((size_t)BB * KSEL * DD * 2);   // reused as h2 (bf16) later
  bf16_t* vb   = (bf16_t*)alloc((size_t)BB * KSEL * DD * 2);
  bf16_t* ctxb = (bf16_t*)alloc((size_t)BB * DD * 2);
  bf16_t* xb   = (bf16_t*)alloc((size_t)BB * DD * 2);
  bf16_t* wqb  = (bf16_t*)alloc((size_t)DD * DD * 2);
  bf16_t* wkb  = (bf16_t*)alloc((size_t)DD * DD * 2);
  bf16_t* wvb  = (bf16_t*)alloc((size_t)DD * DD * 2);
  bf16_t* wob  = (bf16_t*)alloc((size_t)DD * DD * 2);
  bf16_t* w1b  = (bf16_t*)alloc((size_t)HH * DD * 2);
  bf16_t* w2b  = (bf16_t*)alloc((size_t)HH * HH * 2);
  bf16_t* w3b  = (bf16_t*)alloc((size_t)DD * HH * 2);
  bf16_t* h1b  = (bf16_t*)sim;  // 33.5 MB region, free after topk
  bf16_t* h2b  = kb;            // 41.9 MB region, free after attention
  float*  attn_out = (float*)d_out + (size_t)BB * DD;

  auto f2b = [&](const float* in, bf16_t* out, size_t n) {
    f2b_k<<<dim3((unsigned)(n / 1024)), dim3(256), 0, stream>>>(
        (const float4*)in, (ushort4*)out, (int)(n / 4));
  };

  // prep
  f2b(morph0, m0b, (size_t)BB * DD);
  f2b(s0,     s0b, (size_t)NN * DD);
  evo_k<<<dim3((NN * DD) / 1024), dim3(256), 0, stream>>>(
      (const float4*)s0, (const float4*)s1, (ushort4*)evo, (NN * DD) / 4);
  f2b(wq, wqb, (size_t)DD * DD);
  f2b(wk, wkb, (size_t)DD * DD);
  f2b(wv, wvb, (size_t)DD * DD);
  f2b(wo, wob, (size_t)DD * DD);
  f2b(w1, w1b, (size_t)HH * DD);
  f2b(w2, w2b, (size_t)HH * HH);
  f2b(w3, w3b, (size_t)DD * HH);
  rnormd_k<<<dim3(NN), dim3(256), 0, stream>>>(s0, rnd);

  // retrieval
  gemm_bt<false,false,false,false><<<dim3(NN/128, BB/128), dim3(256), 0, stream>>>(
      m0b, s0b, nullptr, nullptr, nullptr, sim, nullptr, BB, NN, DD);
  topk8_k<<<dim3(BB), dim3(256), 0, stream>>>(sim, rnd, cand);
  refine_k<<<dim3(BB), dim3(256), 0, stream>>>(morph0, s0, rnd, cand, tidx);

  // q, k, v
  gemm_bt<false,false,false,true><<<dim3(DD/128, BB/128), dim3(256), 0, stream>>>(
      m0b, wqb, bq, nullptr, nullptr, nullptr, qb, BB, DD, DD);
  gemm_bt<true,false,false,true><<<dim3(DD/128, (BB*KSEL)/128), dim3(256), 0, stream>>>(
      evo, wkb, bk, nullptr, tidx, nullptr, kb, BB*KSEL, DD, DD);
  gemm_bt<true,false,false,true><<<dim3(DD/128, (BB*KSEL)/128), dim3(256), 0, stream>>>(
      evo, wvb, bv, nullptr, tidx, nullptr, vb, BB*KSEL, DD, DD);

  // attention (writes ctx bf16 + attn_weights to d_out tail)
  attn_k<<<dim3(BB), dim3(512), 0, stream>>>(qb, kb, vb, ctxb, attn_out);

  // out-proj + residual -> x ; MLP ; final residual -> predicted
  gemm_bt<false,false,true,true><<<dim3(DD/128, BB/128), dim3(256), 0, stream>>>(
      ctxb, wob, bo, morph0, nullptr, nullptr, xb, BB, DD, DD);
  gemm_bt<false,true,false,true><<<dim3(HH/128, BB/128), dim3(256), 0, stream>>>(
      xb, w1b, b1, nullptr, nullptr, nullptr, h1b, BB, HH, DD);
  gemm_bt<false,true,false,true><<<dim3(HH/128, BB/128), dim3(256), 0, stream>>>(
      h1b, w2b, b2, nullptr, nullptr, nullptr, h2b, BB, HH, HH);
  gemm_bt<false,false,true,false><<<dim3(DD/128, BB/128), dim3(256), 0, stream>>>(
      h2b, w3b, b3, morph0, nullptr, (float*)d_out, nullptr, BB, DD, HH);
}

// Round 3
// 657.691 us; speedup vs baseline: 1.2464x; 1.2464x over previous
//
#include <hip/hip_runtime.h>
#include <hip/hip_bf16.h>
#include <math.h>

typedef __bf16 bf16_t;
typedef __bf16 bf16x4 __attribute__((ext_vector_type(4)));
typedef __bf16 bf16x8 __attribute__((ext_vector_type(8)));
typedef float  f32x4  __attribute__((ext_vector_type(4)));

#define BB 4096
#define NN 2048
#define DD 1024
#define HH 4096
#define KSEL 5
#define NHEAD 8

__device__ __forceinline__ unsigned short bfbits(float f) {
  return __builtin_bit_cast(unsigned short, (bf16_t)f);
}

__device__ __forceinline__ void gload_lds16(const void* g, void* l) {
  __builtin_amdgcn_global_load_lds(
      (const __attribute__((address_space(1))) void*)g,
      (__attribute__((address_space(3))) void*)l, 16, 0, 0);
}

// ---------------- elementwise prep ----------------
__global__ void f2b_k(const float4* __restrict__ in, ushort4* __restrict__ out, int n4) {
  int i = blockIdx.x * 256 + threadIdx.x;
  if (i >= n4) return;
  float4 x = in[i];
  ushort4 o;
  o.x = bfbits(x.x); o.y = bfbits(x.y); o.z = bfbits(x.z); o.w = bfbits(x.w);
  out[i] = o;
}

__global__ void evo_k(const float4* __restrict__ a, const float4* __restrict__ b,
                      ushort4* __restrict__ out, int n4) {
  int i = blockIdx.x * 256 + threadIdx.x;
  if (i >= n4) return;
  float4 x = a[i], y = b[i];
  ushort4 o;
  o.x = bfbits(y.x - x.x); o.y = bfbits(y.y - x.y);
  o.z = bfbits(y.z - x.z); o.w = bfbits(y.w - x.w);
  out[i] = o;
}

// 1/||stored_morph0_n|| in fp64 (used by approx top-k scale and fp64 refine)
__global__ void rnormd_k(const float* __restrict__ s0, double* __restrict__ rnd) {
  __shared__ double red[256];
  int n = blockIdx.x, tid = threadIdx.x;
  const float4* row = (const float4*)(s0 + (size_t)n * DD);
  float4 x = row[tid];
  double ss = (double)x.x * x.x + (double)x.y * x.y + (double)x.z * x.z + (double)x.w * x.w;
  red[tid] = ss; __syncthreads();
  for (int s = 128; s > 0; s >>= 1) {
    if (tid < s) red[tid] += red[tid + s];
    __syncthreads();
  }
  if (tid == 0) rnd[n] = 1.0 / fmax(sqrt(red[0]), 1e-12);
}

// ------- bf16 MFMA GEMM, 2-phase LDS double buffer: C = epi(A[M,K] @ Bw[N,K]^T) -------
template<bool RELU, bool RESID, bool OUTBF16>
__global__ void __launch_bounds__(256)
gemm_bt(const bf16_t* __restrict__ A, const bf16_t* __restrict__ Bw,
        const float* __restrict__ bias, const float* __restrict__ resid,
        float* __restrict__ outf, bf16_t* __restrict__ outb,
        int M, int Nn, int Kk)
{
  __shared__ alignas(16) bf16_t At[2][4096];   // [buf][128 rows][32 k]
  __shared__ alignas(16) bf16_t Bt[2][4096];
  const int tid = threadIdx.x;
  const int wave = tid >> 6, lane = tid & 63;
  const int wm = wave >> 1, wn = wave & 1;
  const int bm = blockIdx.y << 7, bn = blockIdx.x << 7;

  // staging: wave-uniform LDS base + lane*16; source row = (wave*16 + lane/4), colbyte = (lane&3)*16
  const int srow  = (wave << 4) + (lane >> 2);   // 0..63
  const int scolb = (lane & 3) << 4;             // 0,16,32,48
  const char* pA0 = (const char*)A  + (size_t)(bm + srow) * Kk * 2 + scolb;
  const char* pA1 = (const char*)A  + (size_t)(bm + srow + 64) * Kk * 2 + scolb;
  const char* pB0 = (const char*)Bw + (size_t)(bn + srow) * Kk * 2 + scolb;
  const char* pB1 = (const char*)Bw + (size_t)(bn + srow + 64) * Kk * 2 + scolb;

  f32x4 zero = {0.f, 0.f, 0.f, 0.f};
  f32x4 acc[4][4];
  #pragma unroll
  for (int i = 0; i < 4; ++i)
    #pragma unroll
    for (int j = 0; j < 4; ++j) acc[i][j] = zero;

  const int fAoff = ((wm << 6) + (lane & 15)) * 32 + ((lane >> 4) << 3);
  const int fBoff = ((wn << 6) + (lane & 15)) * 32 + ((lane >> 4) << 3);

  const int nt = Kk >> 5;
  // prologue: stage tile 0 into buf 0
  {
    char* lA = (char*)At[0] + (wave << 10);
    char* lB = (char*)Bt[0] + (wave << 10);
    gload_lds16(pA0, lA);
    gload_lds16(pA1, lA + 4096);
    gload_lds16(pB0, lB);
    gload_lds16(pB1, lB + 4096);
  }
  __syncthreads();

  for (int t = 0; t < nt; ++t) {
    const int cur = t & 1;
    if (t + 1 < nt) {
      size_t kb = (size_t)(t + 1) << 6;          // 64 bytes per K-step
      char* lA = (char*)At[cur ^ 1] + (wave << 10);
      char* lB = (char*)Bt[cur ^ 1] + (wave << 10);
      gload_lds16(pA0 + kb, lA);
      gload_lds16(pA1 + kb, lA + 4096);
      gload_lds16(pB0 + kb, lB);
      gload_lds16(pB1 + kb, lB + 4096);
    }
    bf16x8 av[4], bv[4];
    #pragma unroll
    for (int i = 0; i < 4; ++i) av[i] = *(const bf16x8*)(&At[cur][fAoff + i * 512]);
    #pragma unroll
    for (int j = 0; j < 4; ++j) bv[j] = *(const bf16x8*)(&Bt[cur][fBoff + j * 512]);
    #pragma unroll
    for (int i = 0; i < 4; ++i)
      #pragma unroll
      for (int j = 0; j < 4; ++j)
        acc[i][j] = __builtin_amdgcn_mfma_f32_16x16x32_bf16(av[i], bv[j], acc[i][j], 0, 0, 0);
    __syncthreads();   // drains vmcnt (prefetch landed) + lgkmcnt, guards buf reuse
  }

  // C/D layout (m89-verified): col=lane&15, row=(lane>>4)*4+reg
  const int r0 = bm + (wm << 6) + ((lane >> 4) << 2);
  const int c0 = bn + (wn << 6) + (lane & 15);
  #pragma unroll
  for (int i = 0; i < 4; ++i) {
    #pragma unroll
    for (int j = 0; j < 4; ++j) {
      #pragma unroll
      for (int r = 0; r < 4; ++r) {
        int row = r0 + i * 16 + r;
        int col = c0 + j * 16;
        size_t o = (size_t)row * Nn + col;
        float v = acc[i][j][r];
        if (bias)  v += bias[col];
        if (RESID) v += resid[o];
        if (RELU)  v = fmaxf(v, 0.f);
        if (OUTBF16) outb[o] = (bf16_t)v;
        else         outf[o] = v;
      }
    }
  }
}

// ---------------- approx top-8 per row ----------------
__global__ void __launch_bounds__(256)
topk8_k(const float* __restrict__ sim, const double* __restrict__ rnd,
        int* __restrict__ cand)
{
  __shared__ float vals[NN];
  __shared__ float rv[256];
  __shared__ int   ri[256];
  int b = blockIdx.x, tid = threadIdx.x;
  for (int t = 0; t < NN / 256; ++t) {
    int i = tid + t * 256;
    vals[i] = sim[(size_t)b * NN + i] * (float)rnd[i];
  }
  __syncthreads();
  for (int p = 0; p < 8; ++p) {
    float bvv = -INFINITY; int bi = NN;
    for (int t = 0; t < NN / 256; ++t) {
      int i = tid + t * 256;
      float v = vals[i];
      if (v > bvv) { bvv = v; bi = i; }   // strict > keeps lowest index
    }
    rv[tid] = bvv; ri[tid] = bi;
    __syncthreads();
    for (int s = 128; s > 0; s >>= 1) {
      if (tid < s) {
        float v2 = rv[tid + s]; int i2 = ri[tid + s];
        if (v2 > rv[tid] || (v2 == rv[tid] && i2 < ri[tid])) { rv[tid] = v2; ri[tid] = i2; }
      }
      __syncthreads();
    }
    if (tid == 0) {
      int wsel = ri[0];
      cand[b * 8 + p] = wsel;
      vals[wsel] = -INFINITY;
    }
    __syncthreads();
  }
}

// ---------------- fp64 re-rank of the 8 candidates -> exact top-5 ----------------
__global__ void __launch_bounds__(256)
refine_k(const float* __restrict__ m0, const float* __restrict__ s0,
         const double* __restrict__ rnd, const int* __restrict__ cand,
         int* __restrict__ topidx)
{
  __shared__ double red[256];
  __shared__ double vals[8];
  int b = blockIdx.x, tid = threadIdx.x;
  int cs[8];
  #pragma unroll
  for (int j = 0; j < 8; ++j) cs[j] = cand[b * 8 + j];
  const float* q = m0 + (size_t)b * DD;
  double part[8];
  #pragma unroll
  for (int j = 0; j < 8; ++j) part[j] = 0.0;
  for (int d = tid; d < DD; d += 256) {
    double qd = (double)q[d];
    #pragma unroll
    for (int j = 0; j < 8; ++j)
      part[j] += qd * (double)s0[(size_t)cs[j] * DD + d];
  }
  for (int j = 0; j < 8; ++j) {
    red[tid] = part[j]; __syncthreads();
    for (int s = 128; s > 0; s >>= 1) {
      if (tid < s) red[tid] += red[tid + s];
      __syncthreads();
    }
    if (tid == 0) vals[j] = red[0] * rnd[cs[j]];
    __syncthreads();
  }
  if (tid == 0) {
    bool used[8] = {false,false,false,false,false,false,false,false};
    for (int p = 0; p < KSEL; ++p) {
      int best = -1;
      for (int j = 0; j < 8; ++j) {
        if (used[j]) continue;
        if (best < 0 || vals[j] > vals[best] ||
            (vals[j] == vals[best] && cs[j] < cs[best])) best = j;
      }
      used[best] = true;
      topidx[b * KSEL + p] = cs[best];
    }
  }
}

// ---- fused attention: scores from eK gather; ctx[d] = sum_j a_{head(d),j} * eV[idx_j][d] ----
// (per-head weights applied in VALUE space; wo projection stays a separate GEMM)
__global__ void __launch_bounds__(256)
attn_k(const bf16_t* __restrict__ q, const bf16_t* __restrict__ eK,
       const bf16_t* __restrict__ eV, const int* __restrict__ tidx,
       bf16_t* __restrict__ ctx, float* __restrict__ attn_out)
{
  __shared__ float aw[NHEAD][KSEL];
  const int b = blockIdx.x, t = threadIdx.x;
  const int d0 = t << 2;                 // 4 dims per thread; head = t>>5
  int idx[KSEL];
  #pragma unroll
  for (int j = 0; j < KSEL; ++j) idx[j] = tidx[b * KSEL + j];

  bf16x4 qv = *(const bf16x4*)(q + (size_t)b * DD + d0);
  float s[KSEL];
  #pragma unroll
  for (int j = 0; j < KSEL; ++j) {
    bf16x4 kv = *(const bf16x4*)(eK + (size_t)idx[j] * DD + d0);
    float p = (float)qv[0] * (float)kv[0] + (float)qv[1] * (float)kv[1]
            + (float)qv[2] * (float)kv[2] + (float)qv[3] * (float)kv[3];
    #pragma unroll
    for (int m = 16; m > 0; m >>= 1) p += __shfl_xor(p, m);  // reduce 32-thread head group
    s[j] = p * 0.08838834764831845f;     // 1/sqrt(128)
  }
  float mx = s[0];
  #pragma unroll
  for (int j = 1; j < KSEL; ++j) mx = fmaxf(mx, s[j]);
  float e[KSEL], sum = 0.f;
  #pragma unroll
  for (int j = 0; j < KSEL; ++j) { e[j] = expf(s[j] - mx); sum += e[j]; }
  float inv = 1.f / sum;

  float c0 = 0.f, c1 = 0.f, c2 = 0.f, c3 = 0.f;
  #pragma unroll
  for (int j = 0; j < KSEL; ++j) {
    float a = e[j] * inv;
    bf16x4 vv = *(const bf16x4*)(eV + (size_t)idx[j] * DD + d0);
    c0 += a * (float)vv[0]; c1 += a * (float)vv[1];
    c2 += a * (float)vv[2]; c3 += a * (float)vv[3];
    if ((t & 31) == 0) aw[t >> 5][j] = a;
  }
  bf16x4 co; co[0] = (bf16_t)c0; co[1] = (bf16_t)c1; co[2] = (bf16_t)c2; co[3] = (bf16_t)c3;
  *(bf16x4*)(ctx + (size_t)b * DD + d0) = co;
  __syncthreads();
  if (t < KSEL) {
    float m = 0.f;
    #pragma unroll
    for (int hh = 0; hh < NHEAD; ++hh) m += aw[hh][t];
    attn_out[(size_t)b * KSEL + t] = m * 0.125f;
  }
}

// ---------------- launch ----------------
extern "C" void kernel_launch(void* const* d_in, const int* in_sizes, int n_in,
                              void* d_out, int out_size, void* d_ws, size_t ws_size,
                              hipStream_t stream) {
  (void)in_sizes; (void)n_in; (void)out_size; (void)ws_size;
  const float* morph0 = (const float*)d_in[0];
  const float* s0     = (const float*)d_in[1];
  const float* s1     = (const float*)d_in[2];
  const float* wq = (const float*)d_in[3];  const float* bq = (const float*)d_in[4];
  const float* wk = (const float*)d_in[5];  const float* bk = (const float*)d_in[6];
  const float* wv = (const float*)d_in[7];  const float* bv = (const float*)d_in[8];
  const float* wo = (const float*)d_in[9];  const float* bo = (const float*)d_in[10];
  const float* w1 = (const float*)d_in[11]; const float* b1 = (const float*)d_in[12];
  const float* w2 = (const float*)d_in[13]; const float* b2 = (const float*)d_in[14];
  const float* w3 = (const float*)d_in[15]; const float* b3 = (const float*)d_in[16];

  char* ws = (char*)d_ws;
  size_t off = 0;
  auto alloc = [&](size_t bytes) { char* p = ws + off; off += (bytes + 255) & ~(size_t)255; return p; };

  float*  sim  = (float*) alloc((size_t)BB * NN * 4);     // 33.5MB, reused as h1 (bf16) later
  bf16_t* m0b  = (bf16_t*)alloc((size_t)BB * DD * 2);
  bf16_t* s0b  = (bf16_t*)alloc((size_t)NN * DD * 2);
  bf16_t* evo  = (bf16_t*)alloc((size_t)NN * DD * 2);
  double* rnd  = (double*)alloc((size_t)NN * 8);
  int*    cand = (int*)   alloc((size_t)BB * 8 * 4);
  int*    tidx = (int*)   alloc((size_t)BB * KSEL * 4);
  bf16_t* qb   = (bf16_t*)alloc((size_t)BB * DD * 2);
  bf16_t* eKb  = (bf16_t*)alloc((size_t)NN * DD * 2);
  bf16_t* eVb  = (bf16_t*)alloc((size_t)NN * DD * 2);
  bf16_t* ctxb = (bf16_t*)alloc((size_t)BB * DD * 2);
  bf16_t* xb   = (bf16_t*)alloc((size_t)BB * DD * 2);
  bf16_t* wqb  = (bf16_t*)alloc((size_t)DD * DD * 2);
  bf16_t* wkb  = (bf16_t*)alloc((size_t)DD * DD * 2);
  bf16_t* wvb  = (bf16_t*)alloc((size_t)DD * DD * 2);
  bf16_t* wob  = (bf16_t*)alloc((size_t)DD * DD * 2);
  bf16_t* w1b  = (bf16_t*)alloc((size_t)HH * DD * 2);
  bf16_t* w2b  = (bf16_t*)alloc((size_t)HH * HH * 2);
  bf16_t* w3b  = (bf16_t*)alloc((size_t)DD * HH * 2);
  bf16_t* h2b  = (bf16_t*)alloc((size_t)BB * HH * 2);
  bf16_t* h1b  = (bf16_t*)sim;  // alias: sim dead after topk; sizes match (33.5MB)
  float*  attn_out = (float*)d_out + (size_t)BB * DD;

  auto f2b = [&](const float* in, bf16_t* out, size_t n) {
    f2b_k<<<dim3((unsigned)(n / 1024)), dim3(256), 0, stream>>>(
        (const float4*)in, (ushort4*)out, (int)(n / 4));
  };

  // prep
  f2b(morph0, m0b, (size_t)BB * DD);
  f2b(s0,     s0b, (size_t)NN * DD);
  evo_k<<<dim3((NN * DD) / 1024), dim3(256), 0, stream>>>(
      (const float4*)s0, (const float4*)s1, (ushort4*)evo, (NN * DD) / 4);
  f2b(wq, wqb, (size_t)DD * DD);
  f2b(wk, wkb, (size_t)DD * DD);
  f2b(wv, wvb, (size_t)DD * DD);
  f2b(wo, wob, (size_t)DD * DD);
  f2b(w1, w1b, (size_t)HH * DD);
  f2b(w2, w2b, (size_t)HH * HH);
  f2b(w3, w3b, (size_t)DD * HH);
  rnormd_k<<<dim3(NN), dim3(256), 0, stream>>>(s0, rnd);

  // retrieval
  gemm_bt<false,false,false><<<dim3(NN/128, BB/128), dim3(256), 0, stream>>>(
      m0b, s0b, nullptr, nullptr, sim, nullptr, BB, NN, DD);
  topk8_k<<<dim3(BB), dim3(256), 0, stream>>>(sim, rnd, cand);
  refine_k<<<dim3(BB), dim3(256), 0, stream>>>(morph0, s0, rnd, cand, tidx);

  // projections on the 2048 unique evo rows (gather commutes with row-GEMM)
  gemm_bt<false,false,true><<<dim3(DD/128, BB/128), dim3(256), 0, stream>>>(
      m0b, wqb, bq, nullptr, nullptr, qb, BB, DD, DD);
  gemm_bt<false,false,true><<<dim3(DD/128, NN/128), dim3(256), 0, stream>>>(
      evo, wkb, bk, nullptr, nullptr, eKb, NN, DD, DD);
  gemm_bt<false,false,true><<<dim3(DD/128, NN/128), dim3(256), 0, stream>>>(
      evo, wvb, bv, nullptr, nullptr, eVb, NN, DD, DD);

  // fused attention: scores, softmax, ctx (per-head weights in value space); attn_weights out
  attn_k<<<dim3(BB), dim3(256), 0, stream>>>(qb, eKb, eVb, tidx, ctxb, attn_out);

  // out-proj + residual -> x ; MLP ; final residual -> predicted
  gemm_bt<false,true,true><<<dim3(DD/128, BB/128), dim3(256), 0, stream>>>(
      ctxb, wob, bo, morph0, nullptr, xb, BB, DD, DD);
  gemm_bt<true,false,true><<<dim3(HH/128, BB/128), dim3(256), 0, stream>>>(
      xb, w1b, b1, nullptr, nullptr, h1b, BB, HH, DD);
  gemm_bt<true,false,true><<<dim3(HH/128, BB/128), dim3(256), 0, stream>>>(
      h1b, w2b, b2, nullptr, nullptr, h2b, BB, HH, HH);
  gemm_bt<false,true,false><<<dim3(DD/128, BB/128), dim3(256), 0, stream>>>(
      h2b, w3b, b3, morph0, (float*)d_out, nullptr, BB, DD, HH);
}

// Round 4
// 562.894 us; speedup vs baseline: 1.4563x; 1.1684x over previous
//
#include <hip/hip_runtime.h>
#include <hip/hip_bf16.h>
#include <math.h>

typedef __bf16 bf16_t;
typedef __bf16 bf16x4 __attribute__((ext_vector_type(4)));
typedef __bf16 bf16x8 __attribute__((ext_vector_type(8)));
typedef float  f32x4  __attribute__((ext_vector_type(4)));

#define BB 4096
#define NN 2048
#define DD 1024
#define HH 4096
#define KSEL 5
#define NHEAD 8

__device__ __forceinline__ unsigned short bfbits(float f) {
  return __builtin_bit_cast(unsigned short, (bf16_t)f);
}

__device__ __forceinline__ void gload_lds16(const void* g, void* l) {
  __builtin_amdgcn_global_load_lds(
      (const __attribute__((address_space(1))) void*)g,
      (__attribute__((address_space(3))) void*)l, 16, 0, 0);
}

// ---------------- elementwise prep ----------------
__global__ void f2b_k(const float4* __restrict__ in, ushort4* __restrict__ out, int n4) {
  int i = blockIdx.x * 256 + threadIdx.x;
  if (i >= n4) return;
  float4 x = in[i];
  ushort4 o;
  o.x = bfbits(x.x); o.y = bfbits(x.y); o.z = bfbits(x.z); o.w = bfbits(x.w);
  out[i] = o;
}

__global__ void evo_k(const float4* __restrict__ a, const float4* __restrict__ b,
                      ushort4* __restrict__ out, int n4) {
  int i = blockIdx.x * 256 + threadIdx.x;
  if (i >= n4) return;
  float4 x = a[i], y = b[i];
  ushort4 o;
  o.x = bfbits(y.x - x.x); o.y = bfbits(y.y - x.y);
  o.z = bfbits(y.z - x.z); o.w = bfbits(y.w - x.w);
  out[i] = o;
}

// 1/||stored_morph0_n|| in fp64 (used by approx top-k scale and fp64 refine)
__global__ void rnormd_k(const float* __restrict__ s0, double* __restrict__ rnd) {
  __shared__ double red[256];
  int n = blockIdx.x, tid = threadIdx.x;
  const float4* row = (const float4*)(s0 + (size_t)n * DD);
  float4 x = row[tid];
  double ss = (double)x.x * x.x + (double)x.y * x.y + (double)x.z * x.z + (double)x.w * x.w;
  red[tid] = ss; __syncthreads();
  for (int s = 128; s > 0; s >>= 1) {
    if (tid < s) red[tid] += red[tid + s];
    __syncthreads();
  }
  if (tid == 0) rnd[n] = 1.0 / fmax(sqrt(red[0]), 1e-12);
}

// ------- bf16 MFMA GEMM, 2-phase LDS double buffer: C = epi(A[M,K] @ Bw[N,K]^T) -------
// (used for the skinny/medium GEMMs where a 256^2 grid would under-fill the GPU)
template<bool RELU, bool RESID, bool OUTBF16>
__global__ void __launch_bounds__(256)
gemm_bt(const bf16_t* __restrict__ A, const bf16_t* __restrict__ Bw,
        const float* __restrict__ bias, const float* __restrict__ resid,
        float* __restrict__ outf, bf16_t* __restrict__ outb,
        int M, int Nn, int Kk)
{
  __shared__ alignas(16) bf16_t At[2][4096];   // [buf][128 rows][32 k]
  __shared__ alignas(16) bf16_t Bt[2][4096];
  const int tid = threadIdx.x;
  const int wave = tid >> 6, lane = tid & 63;
  const int wm = wave >> 1, wn = wave & 1;
  const int bm = blockIdx.y << 7, bn = blockIdx.x << 7;

  const int srow  = (wave << 4) + (lane >> 2);   // 0..63
  const int scolb = (lane & 3) << 4;             // 0,16,32,48
  const char* pA0 = (const char*)A  + (size_t)(bm + srow) * Kk * 2 + scolb;
  const char* pA1 = (const char*)A  + (size_t)(bm + srow + 64) * Kk * 2 + scolb;
  const char* pB0 = (const char*)Bw + (size_t)(bn + srow) * Kk * 2 + scolb;
  const char* pB1 = (const char*)Bw + (size_t)(bn + srow + 64) * Kk * 2 + scolb;

  f32x4 zero = {0.f, 0.f, 0.f, 0.f};
  f32x4 acc[4][4];
  #pragma unroll
  for (int i = 0; i < 4; ++i)
    #pragma unroll
    for (int j = 0; j < 4; ++j) acc[i][j] = zero;

  const int fAoff = ((wm << 6) + (lane & 15)) * 32 + ((lane >> 4) << 3);
  const int fBoff = ((wn << 6) + (lane & 15)) * 32 + ((lane >> 4) << 3);

  const int nt = Kk >> 5;
  {
    char* lA = (char*)At[0] + (wave << 10);
    char* lB = (char*)Bt[0] + (wave << 10);
    gload_lds16(pA0, lA);
    gload_lds16(pA1, lA + 4096);
    gload_lds16(pB0, lB);
    gload_lds16(pB1, lB + 4096);
  }
  __syncthreads();

  for (int t = 0; t < nt; ++t) {
    const int cur = t & 1;
    if (t + 1 < nt) {
      size_t kb = (size_t)(t + 1) << 6;          // 64 bytes per K-step
      char* lA = (char*)At[cur ^ 1] + (wave << 10);
      char* lB = (char*)Bt[cur ^ 1] + (wave << 10);
      gload_lds16(pA0 + kb, lA);
      gload_lds16(pA1 + kb, lA + 4096);
      gload_lds16(pB0 + kb, lB);
      gload_lds16(pB1 + kb, lB + 4096);
    }
    bf16x8 av[4], bv[4];
    #pragma unroll
    for (int i = 0; i < 4; ++i) av[i] = *(const bf16x8*)(&At[cur][fAoff + i * 512]);
    #pragma unroll
    for (int j = 0; j < 4; ++j) bv[j] = *(const bf16x8*)(&Bt[cur][fBoff + j * 512]);
    #pragma unroll
    for (int i = 0; i < 4; ++i)
      #pragma unroll
      for (int j = 0; j < 4; ++j)
        acc[i][j] = __builtin_amdgcn_mfma_f32_16x16x32_bf16(av[i], bv[j], acc[i][j], 0, 0, 0);
    __syncthreads();
  }

  const int r0 = bm + (wm << 6) + ((lane >> 4) << 2);
  const int c0 = bn + (wn << 6) + (lane & 15);
  #pragma unroll
  for (int i = 0; i < 4; ++i) {
    #pragma unroll
    for (int j = 0; j < 4; ++j) {
      #pragma unroll
      for (int r = 0; r < 4; ++r) {
        int row = r0 + i * 16 + r;
        int col = c0 + j * 16;
        size_t o = (size_t)row * Nn + col;
        float v = acc[i][j][r];
        if (bias)  v += bias[col];
        if (RESID) v += resid[o];
        if (RELU)  v = fmaxf(v, 0.f);
        if (OUTBF16) outb[o] = (bf16_t)v;
        else         outf[o] = v;
      }
    }
  }
}

// ------- 256x256x64 8-wave 4-phase/K-tile MFMA GEMM (m201-style, provably race-free) -----
// C[M,N] = epi(A[M,K] @ Bw[N,K]^T + bias); bf16 out. Requires M%256==0, N%256==0, K%64==0.
// LDS: 2 dbuf x (A 256x64 + B 256x64) bf16 = 128 KiB. XOR swizzle slot^=(row&7) on reads,
// inverse-applied to the per-lane global source of global_load_lds (rule #21).
template<bool RELU>
__global__ void __launch_bounds__(512, 2)
gemm8p(const bf16_t* __restrict__ A, const bf16_t* __restrict__ Bw,
       const float* __restrict__ bias, bf16_t* __restrict__ outb,
       int Nn, int Kk, int nbx)
{
  __shared__ alignas(16) bf16_t As[2][16384];
  __shared__ alignas(16) bf16_t Bs[2][16384];
  const int tid  = threadIdx.x;
  const int lane = tid & 63, wv = tid >> 6;
  const int wm = wv >> 2, wn = wv & 3;          // 2 x 4 waves
  const int ln15 = lane & 15, ln4 = lane >> 4;

  // bijective XCD swizzle (m204)
  const int nwg = gridDim.x;
  const int q = nwg >> 3, r = nwg & 7;
  const int xcd = blockIdx.x & 7, loc = blockIdx.x >> 3;
  const int swz = (xcd < r ? xcd * (q + 1) : r * (q + 1) + (xcd - r) * q) + loc;
  const int bm = (swz / nbx) << 8;
  const int bn = (swz % nbx) << 8;

  const int NT = Kk >> 6;

  f32x4 acc[8][4];
  f32x4 zero = {0.f, 0.f, 0.f, 0.f};
  #pragma unroll
  for (int i = 0; i < 8; ++i)
    #pragma unroll
    for (int j = 0; j < 4; ++j) acc[i][j] = zero;

  // stage one operand tile (256x64) into LDS buf: 4 issues x (8 waves x 64 lanes x 16B)
  // dest (linear): row = e*64 + wv*8 + (lane>>3), slot = lane&7
  // source column pre-swizzled: logical slot = (lane&7) ^ (row&7)
  auto stage = [&](const bf16_t* g, int grow0, bf16_t* lds, int kt) {
    #pragma unroll
    for (int e = 0; e < 4; ++e) {
      int row = e * 64 + wv * 8 + (lane >> 3);
      int slot = (lane & 7) ^ (row & 7);
      gload_lds16(g + (size_t)(grow0 + row) * Kk + kt * 64 + slot * 8,
                  (char*)lds + e * 8192 + wv * 1024);
    }
  };

  stage(A, bm, As[0], 0);
  stage(Bw, bn, Bs[0], 0);
  __syncthreads();

#define DS_A(MH)                                                                 \
    _Pragma("unroll") for (int mi = 0; mi < 4; ++mi)                             \
      _Pragma("unroll") for (int kk = 0; kk < 2; ++kk) {                         \
        const int row = wm * 128 + (MH) * 64 + mi * 16 + ln15;                   \
        const int slot = kk * 4 + ln4;                                           \
        av[mi][kk] = *(const bf16x8*)(Ab + row * 128 + ((slot ^ (row & 7)) << 4)); \
      }
#define DS_B(NH)                                                                 \
    _Pragma("unroll") for (int nj = 0; nj < 2; ++nj)                             \
      _Pragma("unroll") for (int kk = 0; kk < 2; ++kk) {                         \
        const int row = wn * 64 + (NH) * 32 + nj * 16 + ln15;                    \
        const int slot = kk * 4 + ln4;                                           \
        bv[nj][kk] = *(const bf16x8*)(Bb + row * 128 + ((slot ^ (row & 7)) << 4)); \
      }
#define MMA(MH, NH)                                                              \
    __builtin_amdgcn_s_setprio(1);                                               \
    _Pragma("unroll") for (int kk = 0; kk < 2; ++kk)                             \
      _Pragma("unroll") for (int mi = 0; mi < 4; ++mi)                           \
        _Pragma("unroll") for (int nj = 0; nj < 2; ++nj)                         \
          acc[(MH)*4+mi][(NH)*2+nj] = __builtin_amdgcn_mfma_f32_16x16x32_bf16(   \
              av[mi][kk], bv[nj][kk], acc[(MH)*4+mi][(NH)*2+nj], 0, 0, 0);       \
    __builtin_amdgcn_s_setprio(0);

  for (int t = 0; t < NT; ++t) {
    const int cur = t & 1;
    const char* Ab = (const char*)As[cur];
    const char* Bb = (const char*)Bs[cur];
    const bool more = (t + 1 < NT);
    bf16x8 av[4][2], bv[2][2];

    // phase 1: quadrant (mh0, nh0); front-load stage of A(t+1)
    DS_A(0); DS_B(0);
    if (more) stage(A, bm, As[cur ^ 1], t + 1);
    __builtin_amdgcn_s_barrier();
    MMA(0, 0);
    __builtin_amdgcn_s_barrier();

    // phase 2: (mh1, nh0); stage B(t+1)
    DS_A(1);
    if (more) stage(Bw, bn, Bs[cur ^ 1], t + 1);
    __builtin_amdgcn_s_barrier();
    MMA(1, 0);
    __builtin_amdgcn_s_barrier();

    // phase 3: (mh0, nh1)
    DS_A(0); DS_B(1);
    __builtin_amdgcn_s_barrier();
    MMA(0, 1);
    __builtin_amdgcn_s_barrier();

    // phase 4: (mh1, nh1); tile boundary: drain prefetch, then gate
    DS_A(1);
    asm volatile("s_waitcnt vmcnt(0)" ::: "memory");
    __builtin_amdgcn_sched_barrier(0);
    __builtin_amdgcn_s_barrier();
    MMA(1, 1);
    __builtin_amdgcn_s_barrier();
  }
#undef DS_A
#undef DS_B
#undef MMA

  // epilogue: C/D layout col=lane&15, row=(lane>>4)*4+reg
  #pragma unroll
  for (int am = 0; am < 8; ++am) {
    #pragma unroll
    for (int an = 0; an < 4; ++an) {
      #pragma unroll
      for (int rr = 0; rr < 4; ++rr) {
        int row = bm + wm * 128 + am * 16 + (lane >> 4) * 4 + rr;
        int col = bn + wn * 64 + an * 16 + ln15;
        float v = acc[am][an][rr] + bias[col];
        if (RELU) v = fmaxf(v, 0.f);
        outb[(size_t)row * Nn + col] = (bf16_t)v;
      }
    }
  }
}

// ---------------- approx top-8 per row ----------------
__global__ void __launch_bounds__(256)
topk8_k(const float* __restrict__ sim, const double* __restrict__ rnd,
        int* __restrict__ cand)
{
  __shared__ float vals[NN];
  __shared__ float rv[256];
  __shared__ int   ri[256];
  int b = blockIdx.x, tid = threadIdx.x;
  for (int t = 0; t < NN / 256; ++t) {
    int i = tid + t * 256;
    vals[i] = sim[(size_t)b * NN + i] * (float)rnd[i];
  }
  __syncthreads();
  for (int p = 0; p < 8; ++p) {
    float bvv = -INFINITY; int bi = NN;
    for (int t = 0; t < NN / 256; ++t) {
      int i = tid + t * 256;
      float v = vals[i];
      if (v > bvv) { bvv = v; bi = i; }   // strict > keeps lowest index
    }
    rv[tid] = bvv; ri[tid] = bi;
    __syncthreads();
    for (int s = 128; s > 0; s >>= 1) {
      if (tid < s) {
        float v2 = rv[tid + s]; int i2 = ri[tid + s];
        if (v2 > rv[tid] || (v2 == rv[tid] && i2 < ri[tid])) { rv[tid] = v2; ri[tid] = i2; }
      }
      __syncthreads();
    }
    if (tid == 0) {
      int wsel = ri[0];
      cand[b * 8 + p] = wsel;
      vals[wsel] = -INFINITY;
    }
    __syncthreads();
  }
}

// ---------------- fp64 re-rank of the 8 candidates -> exact top-5 ----------------
__global__ void __launch_bounds__(256)
refine_k(const float* __restrict__ m0, const float* __restrict__ s0,
         const double* __restrict__ rnd, const int* __restrict__ cand,
         int* __restrict__ topidx)
{
  __shared__ double red[256];
  __shared__ double vals[8];
  int b = blockIdx.x, tid = threadIdx.x;
  int cs[8];
  #pragma unroll
  for (int j = 0; j < 8; ++j) cs[j] = cand[b * 8 + j];
  const float* q = m0 + (size_t)b * DD;
  double part[8];
  #pragma unroll
  for (int j = 0; j < 8; ++j) part[j] = 0.0;
  for (int d = tid; d < DD; d += 256) {
    double qd = (double)q[d];
    #pragma unroll
    for (int j = 0; j < 8; ++j)
      part[j] += qd * (double)s0[(size_t)cs[j] * DD + d];
  }
  for (int j = 0; j < 8; ++j) {
    red[tid] = part[j]; __syncthreads();
    for (int s = 128; s > 0; s >>= 1) {
      if (tid < s) red[tid] += red[tid + s];
      __syncthreads();
    }
    if (tid == 0) vals[j] = red[0] * rnd[cs[j]];
    __syncthreads();
  }
  if (tid == 0) {
    bool used[8] = {false,false,false,false,false,false,false,false};
    for (int p = 0; p < KSEL; ++p) {
      int best = -1;
      for (int j = 0; j < 8; ++j) {
        if (used[j]) continue;
        if (best < 0 || vals[j] > vals[best] ||
            (vals[j] == vals[best] && cs[j] < cs[best])) best = j;
      }
      used[best] = true;
      topidx[b * KSEL + p] = cs[best];
    }
  }
}

// ---- fused attention: scores from eK gather; ctx[d] = sum_j a_{head(d),j} * eV[idx_j][d] ----
__global__ void __launch_bounds__(256)
attn_k(const bf16_t* __restrict__ q, const bf16_t* __restrict__ eK,
       const bf16_t* __restrict__ eV, const int* __restrict__ tidx,
       bf16_t* __restrict__ ctx, float* __restrict__ attn_out)
{
  __shared__ float aw[NHEAD][KSEL];
  const int b = blockIdx.x, t = threadIdx.x;
  const int d0 = t << 2;                 // 4 dims per thread; head = t>>5
  int idx[KSEL];
  #pragma unroll
  for (int j = 0; j < KSEL; ++j) idx[j] = tidx[b * KSEL + j];

  bf16x4 qv = *(const bf16x4*)(q + (size_t)b * DD + d0);
  float s[KSEL];
  #pragma unroll
  for (int j = 0; j < KSEL; ++j) {
    bf16x4 kv = *(const bf16x4*)(eK + (size_t)idx[j] * DD + d0);
    float p = (float)qv[0] * (float)kv[0] + (float)qv[1] * (float)kv[1]
            + (float)qv[2] * (float)kv[2] + (float)qv[3] * (float)kv[3];
    #pragma unroll
    for (int m = 16; m > 0; m >>= 1) p += __shfl_xor(p, m);  // reduce 32-thread head group
    s[j] = p * 0.08838834764831845f;     // 1/sqrt(128)
  }
  float mx = s[0];
  #pragma unroll
  for (int j = 1; j < KSEL; ++j) mx = fmaxf(mx, s[j]);
  float e[KSEL], sum = 0.f;
  #pragma unroll
  for (int j = 0; j < KSEL; ++j) { e[j] = expf(s[j] - mx); sum += e[j]; }
  float inv = 1.f / sum;

  float c0 = 0.f, c1 = 0.f, c2 = 0.f, c3 = 0.f;
  #pragma unroll
  for (int j = 0; j < KSEL; ++j) {
    float a = e[j] * inv;
    bf16x4 vv = *(const bf16x4*)(eV + (size_t)idx[j] * DD + d0);
    c0 += a * (float)vv[0]; c1 += a * (float)vv[1];
    c2 += a * (float)vv[2]; c3 += a * (float)vv[3];
    if ((t & 31) == 0) aw[t >> 5][j] = a;
  }
  bf16x4 co; co[0] = (bf16_t)c0; co[1] = (bf16_t)c1; co[2] = (bf16_t)c2; co[3] = (bf16_t)c3;
  *(bf16x4*)(ctx + (size_t)b * DD + d0) = co;
  __syncthreads();
  if (t < KSEL) {
    float m = 0.f;
    #pragma unroll
    for (int hh = 0; hh < NHEAD; ++hh) m += aw[hh][t];
    attn_out[(size_t)b * KSEL + t] = m * 0.125f;
  }
}

// ---------------- launch ----------------
extern "C" void kernel_launch(void* const* d_in, const int* in_sizes, int n_in,
                              void* d_out, int out_size, void* d_ws, size_t ws_size,
                              hipStream_t stream) {
  (void)in_sizes; (void)n_in; (void)out_size; (void)ws_size;
  const float* morph0 = (const float*)d_in[0];
  const float* s0     = (const float*)d_in[1];
  const float* s1     = (const float*)d_in[2];
  const float* wq = (const float*)d_in[3];  const float* bq = (const float*)d_in[4];
  const float* wk = (const float*)d_in[5];  const float* bk = (const float*)d_in[6];
  const float* wv = (const float*)d_in[7];  const float* bv = (const float*)d_in[8];
  const float* wo = (const float*)d_in[9];  const float* bo = (const float*)d_in[10];
  const float* w1 = (const float*)d_in[11]; const float* b1 = (const float*)d_in[12];
  const float* w2 = (const float*)d_in[13]; const float* b2 = (const float*)d_in[14];
  const float* w3 = (const float*)d_in[15]; const float* b3 = (const float*)d_in[16];

  char* ws = (char*)d_ws;
  size_t off = 0;
  auto alloc = [&](size_t bytes) { char* p = ws + off; off += (bytes + 255) & ~(size_t)255; return p; };

  float*  sim  = (float*) alloc((size_t)BB * NN * 4);     // 33.5MB, reused as h1 (bf16) later
  bf16_t* m0b  = (bf16_t*)alloc((size_t)BB * DD * 2);
  bf16_t* s0b  = (bf16_t*)alloc((size_t)NN * DD * 2);
  bf16_t* evo  = (bf16_t*)alloc((size_t)NN * DD * 2);
  double* rnd  = (double*)alloc((size_t)NN * 8);
  int*    cand = (int*)   alloc((size_t)BB * 8 * 4);
  int*    tidx = (int*)   alloc((size_t)BB * KSEL * 4);
  bf16_t* qb   = (bf16_t*)alloc((size_t)BB * DD * 2);
  bf16_t* eKb  = (bf16_t*)alloc((size_t)NN * DD * 2);
  bf16_t* eVb  = (bf16_t*)alloc((size_t)NN * DD * 2);
  bf16_t* ctxb = (bf16_t*)alloc((size_t)BB * DD * 2);
  bf16_t* xb   = (bf16_t*)alloc((size_t)BB * DD * 2);
  bf16_t* wqb  = (bf16_t*)alloc((size_t)DD * DD * 2);
  bf16_t* wkb  = (bf16_t*)alloc((size_t)DD * DD * 2);
  bf16_t* wvb  = (bf16_t*)alloc((size_t)DD * DD * 2);
  bf16_t* wob  = (bf16_t*)alloc((size_t)DD * DD * 2);
  bf16_t* w1b  = (bf16_t*)alloc((size_t)HH * DD * 2);
  bf16_t* w2b  = (bf16_t*)alloc((size_t)HH * HH * 2);
  bf16_t* w3b  = (bf16_t*)alloc((size_t)DD * HH * 2);
  bf16_t* h2b  = (bf16_t*)alloc((size_t)BB * HH * 2);
  bf16_t* h1b  = (bf16_t*)sim;  // alias: sim dead after topk; sizes match (33.5MB)
  float*  attn_out = (float*)d_out + (size_t)BB * DD;

  auto f2b = [&](const float* in, bf16_t* out, size_t n) {
    f2b_k<<<dim3((unsigned)(n / 1024)), dim3(256), 0, stream>>>(
        (const float4*)in, (ushort4*)out, (int)(n / 4));
  };

  // prep
  f2b(morph0, m0b, (size_t)BB * DD);
  f2b(s0,     s0b, (size_t)NN * DD);
  evo_k<<<dim3((NN * DD) / 1024), dim3(256), 0, stream>>>(
      (const float4*)s0, (const float4*)s1, (ushort4*)evo, (NN * DD) / 4);
  f2b(wq, wqb, (size_t)DD * DD);
  f2b(wk, wkb, (size_t)DD * DD);
  f2b(wv, wvb, (size_t)DD * DD);
  f2b(wo, wob, (size_t)DD * DD);
  f2b(w1, w1b, (size_t)HH * DD);
  f2b(w2, w2b, (size_t)HH * HH);
  f2b(w3, w3b, (size_t)DD * HH);
  rnormd_k<<<dim3(NN), dim3(256), 0, stream>>>(s0, rnd);

  // retrieval
  gemm_bt<false,false,false><<<dim3(NN/128, BB/128), dim3(256), 0, stream>>>(
      m0b, s0b, nullptr, nullptr, sim, nullptr, BB, NN, DD);
  topk8_k<<<dim3(BB), dim3(256), 0, stream>>>(sim, rnd, cand);
  refine_k<<<dim3(BB), dim3(256), 0, stream>>>(morph0, s0, rnd, cand, tidx);

  // projections on the 2048 unique evo rows (gather commutes with row-GEMM)
  gemm_bt<false,false,true><<<dim3(DD/128, BB/128), dim3(256), 0, stream>>>(
      m0b, wqb, bq, nullptr, nullptr, qb, BB, DD, DD);
  gemm_bt<false,false,true><<<dim3(DD/128, NN/128), dim3(256), 0, stream>>>(
      evo, wkb, bk, nullptr, nullptr, eKb, NN, DD, DD);
  gemm_bt<false,false,true><<<dim3(DD/128, NN/128), dim3(256), 0, stream>>>(
      evo, wvb, bv, nullptr, nullptr, eVb, NN, DD, DD);

  // fused attention: scores, softmax, ctx (per-head weights in value space); attn_weights out
  attn_k<<<dim3(BB), dim3(256), 0, stream>>>(qb, eKb, eVb, tidx, ctxb, attn_out);

  // out-proj + residual -> x
  gemm_bt<false,true,true><<<dim3(DD/128, BB/128), dim3(256), 0, stream>>>(
      ctxb, wob, bo, morph0, nullptr, xb, BB, DD, DD);

  // MLP: big square GEMMs on the 8-phase 256^2 kernel
  gemm8p<true><<<dim3((BB/256)*(HH/256)), dim3(512), 0, stream>>>(
      xb, w1b, b1, h1b, HH, DD, HH/256);
  gemm8p<true><<<dim3((BB/256)*(HH/256)), dim3(512), 0, stream>>>(
      h1b, w2b, b2, h2b, HH, HH, HH/256);
  gemm_bt<false,true,false><<<dim3(DD/128, BB/128), dim3(256), 0, stream>>>(
      h2b, w3b, b3, morph0, (float*)d_out, nullptr, BB, DD, HH);
}

// Round 5
// 549.194 us; speedup vs baseline: 1.4926x; 1.0249x over previous
//
#include <hip/hip_runtime.h>
#include <hip/hip_bf16.h>
#include <math.h>

typedef __bf16 bf16_t;
typedef __bf16 bf16x4 __attribute__((ext_vector_type(4)));
typedef __bf16 bf16x8 __attribute__((ext_vector_type(8)));
typedef float  f32x4  __attribute__((ext_vector_type(4)));

#define BB 4096
#define NN 2048
#define DD 1024
#define HH 4096
#define KSEL 5
#define NHEAD 8

__device__ __forceinline__ unsigned short bfbits(float f) {
  return __builtin_bit_cast(unsigned short, (bf16_t)f);
}

__device__ __forceinline__ void gload_lds16(const void* g, void* l) {
  __builtin_amdgcn_global_load_lds(
      (const __attribute__((address_space(1))) void*)g,
      (__attribute__((address_space(3))) void*)l, 16, 0, 0);
}

__device__ __forceinline__ ushort4 cvt4(float4 x) {
  ushort4 o;
  o.x = bfbits(x.x); o.y = bfbits(x.y); o.z = bfbits(x.z); o.w = bfbits(x.w);
  return o;
}

// ---------------- fused fp32->bf16 prep (all conversions in one launch) ----------------
// segments (float4 units, cumulative):
#define P_M0   1048576
#define P_S0   1572864
#define P_EVO  2097152
#define P_WQ   2359296
#define P_WK   2621440
#define P_WV   2883584
#define P_WO   3145728
#define P_W1   4194304
#define P_W2   8388608
#define P_W3   9437184
__global__ void __launch_bounds__(256)
prep_k(const float4* __restrict__ m0, const float4* __restrict__ s0,
       const float4* __restrict__ s1,
       const float4* __restrict__ wq, const float4* __restrict__ wk,
       const float4* __restrict__ wv, const float4* __restrict__ wo,
       const float4* __restrict__ w1, const float4* __restrict__ w2,
       const float4* __restrict__ w3,
       ushort4* __restrict__ m0b, ushort4* __restrict__ s0b,
       ushort4* __restrict__ evo,
       ushort4* __restrict__ wqb, ushort4* __restrict__ wkb,
       ushort4* __restrict__ wvb, ushort4* __restrict__ wob,
       ushort4* __restrict__ w1b, ushort4* __restrict__ w2b,
       ushort4* __restrict__ w3b)
{
  const int stride = gridDim.x * 256;
  for (int i = blockIdx.x * 256 + threadIdx.x; i < P_W3; i += stride) {
    if (i < P_M0) {
      m0b[i] = cvt4(m0[i]);
    } else if (i < P_S0) {
      int j = i - P_M0; s0b[j] = cvt4(s0[j]);
    } else if (i < P_EVO) {
      int j = i - P_S0;
      float4 a = s0[j], b = s1[j];
      float4 d; d.x = b.x - a.x; d.y = b.y - a.y; d.z = b.z - a.z; d.w = b.w - a.w;
      evo[j] = cvt4(d);
    } else if (i < P_WQ) {
      int j = i - P_EVO; wqb[j] = cvt4(wq[j]);
    } else if (i < P_WK) {
      int j = i - P_WQ; wkb[j] = cvt4(wk[j]);
    } else if (i < P_WV) {
      int j = i - P_WK; wvb[j] = cvt4(wv[j]);
    } else if (i < P_WO) {
      int j = i - P_WV; wob[j] = cvt4(wo[j]);
    } else if (i < P_W1) {
      int j = i - P_WO; w1b[j] = cvt4(w1[j]);
    } else if (i < P_W2) {
      int j = i - P_W1; w2b[j] = cvt4(w2[j]);
    } else {
      int j = i - P_W2; w3b[j] = cvt4(w3[j]);
    }
  }
}

// 1/||stored_morph0_n|| in fp64 (used by approx top-k scale and fp64 refine)
__global__ void rnormd_k(const float* __restrict__ s0, double* __restrict__ rnd) {
  __shared__ double red[256];
  int n = blockIdx.x, tid = threadIdx.x;
  const float4* row = (const float4*)(s0 + (size_t)n * DD);
  float4 x = row[tid];
  double ss = (double)x.x * x.x + (double)x.y * x.y + (double)x.z * x.z + (double)x.w * x.w;
  red[tid] = ss; __syncthreads();
  for (int s = 128; s > 0; s >>= 1) {
    if (tid < s) red[tid] += red[tid + s];
    __syncthreads();
  }
  if (tid == 0) rnd[n] = 1.0 / fmax(sqrt(red[0]), 1e-12);
}

// ------- bf16 MFMA GEMM, 2-phase LDS double buffer: C = epi(A[M,K] @ Bw[N,K]^T) -------
// (used for the skinny/medium GEMMs where a 256^2 grid would under-fill the GPU)
template<bool RELU, bool RESID, bool OUTBF16>
__global__ void __launch_bounds__(256)
gemm_bt(const bf16_t* __restrict__ A, const bf16_t* __restrict__ Bw,
        const float* __restrict__ bias, const float* __restrict__ resid,
        float* __restrict__ outf, bf16_t* __restrict__ outb,
        int M, int Nn, int Kk)
{
  __shared__ alignas(16) bf16_t At[2][4096];   // [buf][128 rows][32 k]
  __shared__ alignas(16) bf16_t Bt[2][4096];
  const int tid = threadIdx.x;
  const int wave = tid >> 6, lane = tid & 63;
  const int wm = wave >> 1, wn = wave & 1;
  const int bm = blockIdx.y << 7, bn = blockIdx.x << 7;

  const int srow  = (wave << 4) + (lane >> 2);   // 0..63
  const int scolb = (lane & 3) << 4;             // 0,16,32,48
  const char* pA0 = (const char*)A  + (size_t)(bm + srow) * Kk * 2 + scolb;
  const char* pA1 = (const char*)A  + (size_t)(bm + srow + 64) * Kk * 2 + scolb;
  const char* pB0 = (const char*)Bw + (size_t)(bn + srow) * Kk * 2 + scolb;
  const char* pB1 = (const char*)Bw + (size_t)(bn + srow + 64) * Kk * 2 + scolb;

  f32x4 zero = {0.f, 0.f, 0.f, 0.f};
  f32x4 acc[4][4];
  #pragma unroll
  for (int i = 0; i < 4; ++i)
    #pragma unroll
    for (int j = 0; j < 4; ++j) acc[i][j] = zero;

  const int fAoff = ((wm << 6) + (lane & 15)) * 32 + ((lane >> 4) << 3);
  const int fBoff = ((wn << 6) + (lane & 15)) * 32 + ((lane >> 4) << 3);

  const int nt = Kk >> 5;
  {
    char* lA = (char*)At[0] + (wave << 10);
    char* lB = (char*)Bt[0] + (wave << 10);
    gload_lds16(pA0, lA);
    gload_lds16(pA1, lA + 4096);
    gload_lds16(pB0, lB);
    gload_lds16(pB1, lB + 4096);
  }
  __syncthreads();

  for (int t = 0; t < nt; ++t) {
    const int cur = t & 1;
    if (t + 1 < nt) {
      size_t kb = (size_t)(t + 1) << 6;          // 64 bytes per K-step
      char* lA = (char*)At[cur ^ 1] + (wave << 10);
      char* lB = (char*)Bt[cur ^ 1] + (wave << 10);
      gload_lds16(pA0 + kb, lA);
      gload_lds16(pA1 + kb, lA + 4096);
      gload_lds16(pB0 + kb, lB);
      gload_lds16(pB1 + kb, lB + 4096);
    }
    bf16x8 av[4], bv[4];
    #pragma unroll
    for (int i = 0; i < 4; ++i) av[i] = *(const bf16x8*)(&At[cur][fAoff + i * 512]);
    #pragma unroll
    for (int j = 0; j < 4; ++j) bv[j] = *(const bf16x8*)(&Bt[cur][fBoff + j * 512]);
    #pragma unroll
    for (int i = 0; i < 4; ++i)
      #pragma unroll
      for (int j = 0; j < 4; ++j)
        acc[i][j] = __builtin_amdgcn_mfma_f32_16x16x32_bf16(av[i], bv[j], acc[i][j], 0, 0, 0);
    __syncthreads();
  }

  const int r0 = bm + (wm << 6) + ((lane >> 4) << 2);
  const int c0 = bn + (wn << 6) + (lane & 15);
  #pragma unroll
  for (int i = 0; i < 4; ++i) {
    #pragma unroll
    for (int j = 0; j < 4; ++j) {
      #pragma unroll
      for (int r = 0; r < 4; ++r) {
        int row = r0 + i * 16 + r;
        int col = c0 + j * 16;
        size_t o = (size_t)row * Nn + col;
        float v = acc[i][j][r];
        if (bias)  v += bias[col];
        if (RESID) v += resid[o];
        if (RELU)  v = fmaxf(v, 0.f);
        if (OUTBF16) outb[o] = (bf16_t)v;
        else         outf[o] = v;
      }
    }
  }
}

// ------- 256x256x64 8-wave MFMA GEMM with counted-vmcnt staggered pipeline (T3+T4) -----
// C[M,N] = epi(A[M,K] @ Bw[N,K]^T + bias); bf16 out. M%256==0, N%256==0, K%64==0.
// LDS: 2 dbuf x (A 256x64 + B 256x64) bf16 = 128 KiB. XOR swizzle slot^=(row&7) on reads,
// inverse-applied to the per-lane global source of global_load_lds (rule #21).
// Region-stages: A by m-half (rows [MH*64,+64) u [128+MH*64,+64)), B by n-half (bit5=NH).
// Issue order/wave: sA0@P1 sB0@P2 sA1@P3 sB1@P4; gates vmcnt(4) at end of P4,P1,P2.
// Safety: every staged region's last reader finished >=1 barrier before the stage issue;
// identical per-wave issue sequence + vmcnt(4)+barrier makes the wait cross-wave valid.
template<bool RELU>
__global__ void __launch_bounds__(512, 2)
gemm8p(const bf16_t* __restrict__ A, const bf16_t* __restrict__ Bw,
       const float* __restrict__ bias, bf16_t* __restrict__ outb,
       int Nn, int Kk, int nbx)
{
  __shared__ alignas(16) bf16_t As[2][16384];
  __shared__ alignas(16) bf16_t Bs[2][16384];
  const int tid  = threadIdx.x;
  const int lane = tid & 63, wv = tid >> 6;
  const int wm = wv >> 2, wn = wv & 3;          // 2 x 4 waves
  const int ln15 = lane & 15, ln4 = lane >> 4;

  // bijective XCD swizzle (m204)
  const int nwg = gridDim.x;
  const int q = nwg >> 3, r = nwg & 7;
  const int xcd = blockIdx.x & 7, loc = blockIdx.x >> 3;
  const int swz = (xcd < r ? xcd * (q + 1) : r * (q + 1) + (xcd - r) * q) + loc;
  const int bm = (swz / nbx) << 8;
  const int bn = (swz % nbx) << 8;

  const int NT = Kk >> 6;

  f32x4 acc[8][4];
  f32x4 zero = {0.f, 0.f, 0.f, 0.f};
  #pragma unroll
  for (int i = 0; i < 8; ++i)
    #pragma unroll
    for (int j = 0; j < 4; ++j) acc[i][j] = zero;

  // stage A region MH of tile kt: 2 x 64-row issues; dest linear (rowbase*128 + lane*16)
  auto stageA = [&](int MH, bf16_t* lds, int kt) {
    #pragma unroll
    for (int u = 0; u < 2; ++u) {
      int rowbase = u * 128 + MH * 64 + wv * 8;
      int row = rowbase + (lane >> 3);
      int slot = (lane & 7) ^ (row & 7);
      gload_lds16(A + (size_t)(bm + row) * Kk + kt * 64 + slot * 8,
                  (char*)lds + rowbase * 128);
    }
  };
  // stage B region NH (rows with bit5==NH): 2 x 64-row issues
  auto stageB = [&](int NH, bf16_t* lds, int kt) {
    #pragma unroll
    for (int u = 0; u < 2; ++u) {
      int rowbase = u * 128 + ((wv >> 2) << 6) + NH * 32 + ((wv & 3) << 3);
      int row = rowbase + (lane >> 3);
      int slot = (lane & 7) ^ (row & 7);
      gload_lds16(Bw + (size_t)(bn + row) * Kk + kt * 64 + slot * 8,
                  (char*)lds + rowbase * 128);
    }
  };

  // prologue: full tile 0, hard drain
  stageA(0, As[0], 0); stageA(1, As[0], 0);
  stageB(0, Bs[0], 0); stageB(1, Bs[0], 0);
  asm volatile("s_waitcnt vmcnt(0)" ::: "memory");
  __builtin_amdgcn_s_barrier();

#define DS_A(MH)                                                                 \
    _Pragma("unroll") for (int mi = 0; mi < 4; ++mi)                             \
      _Pragma("unroll") for (int kk = 0; kk < 2; ++kk) {                         \
        const int row = wm * 128 + (MH) * 64 + mi * 16 + ln15;                   \
        const int slot = kk * 4 + ln4;                                           \
        av[mi][kk] = *(const bf16x8*)(Ab + row * 128 + ((slot ^ (row & 7)) << 4)); \
      }
#define DS_B(NH)                                                                 \
    _Pragma("unroll") for (int nj = 0; nj < 2; ++nj)                             \
      _Pragma("unroll") for (int kk = 0; kk < 2; ++kk) {                         \
        const int row = wn * 64 + (NH) * 32 + nj * 16 + ln15;                    \
        const int slot = kk * 4 + ln4;                                           \
        bv[nj][kk] = *(const bf16x8*)(Bb + row * 128 + ((slot ^ (row & 7)) << 4)); \
      }
#define MMA(MH, NH)                                                              \
    __builtin_amdgcn_s_setprio(1);                                               \
    _Pragma("unroll") for (int kk = 0; kk < 2; ++kk)                             \
      _Pragma("unroll") for (int mi = 0; mi < 4; ++mi)                           \
        _Pragma("unroll") for (int nj = 0; nj < 2; ++nj)                         \
          acc[(MH)*4+mi][(NH)*2+nj] = __builtin_amdgcn_mfma_f32_16x16x32_bf16(   \
              av[mi][kk], bv[nj][kk], acc[(MH)*4+mi][(NH)*2+nj], 0, 0, 0);       \
    __builtin_amdgcn_s_setprio(0);
#define VMW4                                                                     \
    asm volatile("s_waitcnt vmcnt(4)" ::: "memory");                             \
    __builtin_amdgcn_sched_barrier(0);

  for (int t = 0; t < NT; ++t) {
    const int cur = t & 1;
    const char* Ab = (const char*)As[cur];
    const char* Bb = (const char*)Bs[cur];
    bf16_t* nA = As[cur ^ 1];
    bf16_t* nB = Bs[cur ^ 1];
    const bool more = (t + 1 < NT);
    bf16x8 av[4][2], bv[2][2];

    // P1: MMA(0,0) reads A0,B0; stage sA0(t+1); gate(end): sA1(t) landed for P2
    DS_A(0); DS_B(0);
    if (more) stageA(0, nA, t + 1);
    __builtin_amdgcn_s_barrier();
    MMA(0, 0);
    VMW4;
    __builtin_amdgcn_s_barrier();

    // P2: MMA(1,0) reads A1 (B0 in regs); stage sB0(t+1); gate(end): sB1(t) landed for P3
    DS_A(1);
    if (more) stageB(0, nB, t + 1);
    __builtin_amdgcn_s_barrier();
    MMA(1, 0);
    VMW4;
    __builtin_amdgcn_s_barrier();

    // P3: MMA(0,1) reads A0,B1; stage sA1(t+1); no vm gate
    DS_A(0); DS_B(1);
    if (more) stageA(1, nA, t + 1);
    __builtin_amdgcn_s_barrier();
    MMA(0, 1);
    __builtin_amdgcn_s_barrier();

    // P4: MMA(1,1) reads A1 (B1 in regs); stage sB1(t+1);
    // gate(end): sA0,sB0(t+1) landed for next P1
    DS_A(1);
    if (more) stageB(1, nB, t + 1);
    __builtin_amdgcn_s_barrier();
    MMA(1, 1);
    VMW4;
    __builtin_amdgcn_s_barrier();
  }
#undef DS_A
#undef DS_B
#undef MMA
#undef VMW4

  // epilogue: C/D layout col=lane&15, row=(lane>>4)*4+reg
  #pragma unroll
  for (int am = 0; am < 8; ++am) {
    #pragma unroll
    for (int an = 0; an < 4; ++an) {
      #pragma unroll
      for (int rr = 0; rr < 4; ++rr) {
        int row = bm + wm * 128 + am * 16 + (lane >> 4) * 4 + rr;
        int col = bn + wn * 64 + an * 16 + ln15;
        float v = acc[am][an][rr] + bias[col];
        if (RELU) v = fmaxf(v, 0.f);
        outb[(size_t)row * Nn + col] = (bf16_t)v;
      }
    }
  }
}

// ---------------- approx top-8 per row ----------------
__global__ void __launch_bounds__(256)
topk8_k(const float* __restrict__ sim, const double* __restrict__ rnd,
        int* __restrict__ cand)
{
  __shared__ float vals[NN];
  __shared__ float rv[256];
  __shared__ int   ri[256];
  int b = blockIdx.x, tid = threadIdx.x;
  for (int t = 0; t < NN / 256; ++t) {
    int i = tid + t * 256;
    vals[i] = sim[(size_t)b * NN + i] * (float)rnd[i];
  }
  __syncthreads();
  for (int p = 0; p < 8; ++p) {
    float bvv = -INFINITY; int bi = NN;
    for (int t = 0; t < NN / 256; ++t) {
      int i = tid + t * 256;
      float v = vals[i];
      if (v > bvv) { bvv = v; bi = i; }   // strict > keeps lowest index
    }
    rv[tid] = bvv; ri[tid] = bi;
    __syncthreads();
    for (int s = 128; s > 0; s >>= 1) {
      if (tid < s) {
        float v2 = rv[tid + s]; int i2 = ri[tid + s];
        if (v2 > rv[tid] || (v2 == rv[tid] && i2 < ri[tid])) { rv[tid] = v2; ri[tid] = i2; }
      }
      __syncthreads();
    }
    if (tid == 0) {
      int wsel = ri[0];
      cand[b * 8 + p] = wsel;
      vals[wsel] = -INFINITY;
    }
    __syncthreads();
  }
}

// ---------------- fp64 re-rank of the 8 candidates -> exact top-5 ----------------
__global__ void __launch_bounds__(256)
refine_k(const float* __restrict__ m0, const float* __restrict__ s0,
         const double* __restrict__ rnd, const int* __restrict__ cand,
         int* __restrict__ topidx)
{
  __shared__ double red[256];
  __shared__ double vals[8];
  int b = blockIdx.x, tid = threadIdx.x;
  int cs[8];
  #pragma unroll
  for (int j = 0; j < 8; ++j) cs[j] = cand[b * 8 + j];
  const float* q = m0 + (size_t)b * DD;
  double part[8];
  #pragma unroll
  for (int j = 0; j < 8; ++j) part[j] = 0.0;
  for (int d = tid; d < DD; d += 256) {
    double qd = (double)q[d];
    #pragma unroll
    for (int j = 0; j < 8; ++j)
      part[j] += qd * (double)s0[(size_t)cs[j] * DD + d];
  }
  for (int j = 0; j < 8; ++j) {
    red[tid] = part[j]; __syncthreads();
    for (int s = 128; s > 0; s >>= 1) {
      if (tid < s) red[tid] += red[tid + s];
      __syncthreads();
    }
    if (tid == 0) vals[j] = red[0] * rnd[cs[j]];
    __syncthreads();
  }
  if (tid == 0) {
    bool used[8] = {false,false,false,false,false,false,false,false};
    for (int p = 0; p < KSEL; ++p) {
      int best = -1;
      for (int j = 0; j < 8; ++j) {
        if (used[j]) continue;
        if (best < 0 || vals[j] > vals[best] ||
            (vals[j] == vals[best] && cs[j] < cs[best])) best = j;
      }
      used[best] = true;
      topidx[b * KSEL + p] = cs[best];
    }
  }
}

// ---- fused attention: scores from eK gather; ctx[d] = sum_j a_{head(d),j} * eV[idx_j][d] ----
__global__ void __launch_bounds__(256)
attn_k(const bf16_t* __restrict__ q, const bf16_t* __restrict__ eK,
       const bf16_t* __restrict__ eV, const int* __restrict__ tidx,
       bf16_t* __restrict__ ctx, float* __restrict__ attn_out)
{
  __shared__ float aw[NHEAD][KSEL];
  const int b = blockIdx.x, t = threadIdx.x;
  const int d0 = t << 2;                 // 4 dims per thread; head = t>>5
  int idx[KSEL];
  #pragma unroll
  for (int j = 0; j < KSEL; ++j) idx[j] = tidx[b * KSEL + j];

  bf16x4 qv = *(const bf16x4*)(q + (size_t)b * DD + d0);
  float s[KSEL];
  #pragma unroll
  for (int j = 0; j < KSEL; ++j) {
    bf16x4 kv = *(const bf16x4*)(eK + (size_t)idx[j] * DD + d0);
    float p = (float)qv[0] * (float)kv[0] + (float)qv[1] * (float)kv[1]
            + (float)qv[2] * (float)kv[2] + (float)qv[3] * (float)kv[3];
    #pragma unroll
    for (int m = 16; m > 0; m >>= 1) p += __shfl_xor(p, m);  // reduce 32-thread head group
    s[j] = p * 0.08838834764831845f;     // 1/sqrt(128)
  }
  float mx = s[0];
  #pragma unroll
  for (int j = 1; j < KSEL; ++j) mx = fmaxf(mx, s[j]);
  float e[KSEL], sum = 0.f;
  #pragma unroll
  for (int j = 0; j < KSEL; ++j) { e[j] = expf(s[j] - mx); sum += e[j]; }
  float inv = 1.f / sum;

  float c0 = 0.f, c1 = 0.f, c2 = 0.f, c3 = 0.f;
  #pragma unroll
  for (int j = 0; j < KSEL; ++j) {
    float a = e[j] * inv;
    bf16x4 vv = *(const bf16x4*)(eV + (size_t)idx[j] * DD + d0);
    c0 += a * (float)vv[0]; c1 += a * (float)vv[1];
    c2 += a * (float)vv[2]; c3 += a * (float)vv[3];
    if ((t & 31) == 0) aw[t >> 5][j] = a;
  }
  bf16x4 co; co[0] = (bf16_t)c0; co[1] = (bf16_t)c1; co[2] = (bf16_t)c2; co[3] = (bf16_t)c3;
  *(bf16x4*)(ctx + (size_t)b * DD + d0) = co;
  __syncthreads();
  if (t < KSEL) {
    float m = 0.f;
    #pragma unroll
    for (int hh = 0; hh < NHEAD; ++hh) m += aw[hh][t];
    attn_out[(size_t)b * KSEL + t] = m * 0.125f;
  }
}

// ---------------- launch ----------------
extern "C" void kernel_launch(void* const* d_in, const int* in_sizes, int n_in,
                              void* d_out, int out_size, void* d_ws, size_t ws_size,
                              hipStream_t stream) {
  (void)in_sizes; (void)n_in; (void)out_size; (void)ws_size;
  const float* morph0 = (const float*)d_in[0];
  const float* s0     = (const float*)d_in[1];
  const float* s1     = (const float*)d_in[2];
  const float* wq = (const float*)d_in[3];  const float* bq = (const float*)d_in[4];
  const float* wk = (const float*)d_in[5];  const float* bk = (const float*)d_in[6];
  const float* wv = (const float*)d_in[7];  const float* bv = (const float*)d_in[8];
  const float* wo = (const float*)d_in[9];  const float* bo = (const float*)d_in[10];
  const float* w1 = (const float*)d_in[11]; const float* b1 = (const float*)d_in[12];
  const float* w2 = (const float*)d_in[13]; const float* b2 = (const float*)d_in[14];
  const float* w3 = (const float*)d_in[15]; const float* b3 = (const float*)d_in[16];

  char* ws = (char*)d_ws;
  size_t off = 0;
  auto alloc = [&](size_t bytes) { char* p = ws + off; off += (bytes + 255) & ~(size_t)255; return p; };

  float*  sim  = (float*) alloc((size_t)BB * NN * 4);     // 33.5MB, reused as h1 (bf16) later
  bf16_t* m0b  = (bf16_t*)alloc((size_t)BB * DD * 2);
  bf16_t* s0b  = (bf16_t*)alloc((size_t)NN * DD * 2);
  bf16_t* evo  = (bf16_t*)alloc((size_t)NN * DD * 2);
  double* rnd  = (double*)alloc((size_t)NN * 8);
  int*    cand = (int*)   alloc((size_t)BB * 8 * 4);
  int*    tidx = (int*)   alloc((size_t)BB * KSEL * 4);
  bf16_t* qb   = (bf16_t*)alloc((size_t)BB * DD * 2);
  bf16_t* eKb  = (bf16_t*)alloc((size_t)NN * DD * 2);
  bf16_t* eVb  = (bf16_t*)alloc((size_t)NN * DD * 2);
  bf16_t* ctxb = (bf16_t*)alloc((size_t)BB * DD * 2);
  bf16_t* xb   = (bf16_t*)alloc((size_t)BB * DD * 2);
  bf16_t* wqb  = (bf16_t*)alloc((size_t)DD * DD * 2);
  bf16_t* wkb  = (bf16_t*)alloc((size_t)DD * DD * 2);
  bf16_t* wvb  = (bf16_t*)alloc((size_t)DD * DD * 2);
  bf16_t* wob  = (bf16_t*)alloc((size_t)DD * DD * 2);
  bf16_t* w1b  = (bf16_t*)alloc((size_t)HH * DD * 2);
  bf16_t* w2b  = (bf16_t*)alloc((size_t)HH * HH * 2);
  bf16_t* w3b  = (bf16_t*)alloc((size_t)DD * HH * 2);
  bf16_t* h2b  = (bf16_t*)alloc((size_t)BB * HH * 2);
  bf16_t* h1b  = (bf16_t*)sim;  // alias: sim dead after topk; sizes match (33.5MB)
  float*  attn_out = (float*)d_out + (size_t)BB * DD;

  // fused prep: all fp32->bf16 conversions + evo in one launch
  prep_k<<<dim3(2048), dim3(256), 0, stream>>>(
      (const float4*)morph0, (const float4*)s0, (const float4*)s1,
      (const float4*)wq, (const float4*)wk, (const float4*)wv, (const float4*)wo,
      (const float4*)w1, (const float4*)w2, (const float4*)w3,
      (ushort4*)m0b, (ushort4*)s0b, (ushort4*)evo,
      (ushort4*)wqb, (ushort4*)wkb, (ushort4*)wvb, (ushort4*)wob,
      (ushort4*)w1b, (ushort4*)w2b, (ushort4*)w3b);
  rnormd_k<<<dim3(NN), dim3(256), 0, stream>>>(s0, rnd);

  // retrieval
  gemm_bt<false,false,false><<<dim3(NN/128, BB/128), dim3(256), 0, stream>>>(
      m0b, s0b, nullptr, nullptr, sim, nullptr, BB, NN, DD);
  topk8_k<<<dim3(BB), dim3(256), 0, stream>>>(sim, rnd, cand);
  refine_k<<<dim3(BB), dim3(256), 0, stream>>>(morph0, s0, rnd, cand, tidx);

  // projections on the 2048 unique evo rows (gather commutes with row-GEMM)
  gemm_bt<false,false,true><<<dim3(DD/128, BB/128), dim3(256), 0, stream>>>(
      m0b, wqb, bq, nullptr, nullptr, qb, BB, DD, DD);
  gemm_bt<false,false,true><<<dim3(DD/128, NN/128), dim3(256), 0, stream>>>(
      evo, wkb, bk, nullptr, nullptr, eKb, NN, DD, DD);
  gemm_bt<false,false,true><<<dim3(DD/128, NN/128), dim3(256), 0, stream>>>(
      evo, wvb, bv, nullptr, nullptr, eVb, NN, DD, DD);

  // fused attention: scores, softmax, ctx (per-head weights in value space); attn_weights out
  attn_k<<<dim3(BB), dim3(256), 0, stream>>>(qb, eKb, eVb, tidx, ctxb, attn_out);

  // out-proj + residual -> x
  gemm_bt<false,true,true><<<dim3(DD/128, BB/128), dim3(256), 0, stream>>>(
      ctxb, wob, bo, morph0, nullptr, xb, BB, DD, DD);

  // MLP: big square GEMMs on the staggered-pipeline 256^2 kernel
  gemm8p<true><<<dim3((BB/256)*(HH/256)), dim3(512), 0, stream>>>(
      xb, w1b, b1, h1b, HH, DD, HH/256);
  gemm8p<true><<<dim3((BB/256)*(HH/256)), dim3(512), 0, stream>>>(
      h1b, w2b, b2, h2b, HH, HH, HH/256);
  gemm_bt<false,true,false><<<dim3(DD/128, BB/128), dim3(256), 0, stream>>>(
      h2b, w3b, b3, morph0, (float*)d_out, nullptr, BB, DD, HH);
}

// Round 6
// 534.032 us; speedup vs baseline: 1.5350x; 1.0284x over previous
//
#include <hip/hip_runtime.h>
#include <hip/hip_bf16.h>
#include <math.h>

typedef __bf16 bf16_t;
typedef __bf16 bf16x4 __attribute__((ext_vector_type(4)));
typedef __bf16 bf16x8 __attribute__((ext_vector_type(8)));
typedef float  f32x4  __attribute__((ext_vector_type(4)));

#define BB 4096
#define NN 2048
#define DD 1024
#define HH 4096
#define KSEL 5
#define NHEAD 8

__device__ __forceinline__ unsigned short bfbits(float f) {
  return __builtin_bit_cast(unsigned short, (bf16_t)f);
}

__device__ __forceinline__ void gload_lds16(const void* g, void* l) {
  __builtin_amdgcn_global_load_lds(
      (const __attribute__((address_space(1))) void*)g,
      (__attribute__((address_space(3))) void*)l, 16, 0, 0);
}

__device__ __forceinline__ ushort4 cvt4(float4 x) {
  ushort4 o;
  o.x = bfbits(x.x); o.y = bfbits(x.y); o.z = bfbits(x.z); o.w = bfbits(x.w);
  return o;
}

// ---------------- fused fp32->bf16 prep (all conversions in one launch) ----------------
// segments (float4 units, cumulative):
#define P_M0   1048576
#define P_S0   1572864
#define P_EVO  2097152
#define P_WQ   2359296
#define P_WK   2621440
#define P_WV   2883584
#define P_WO   3145728
#define P_W1   4194304
#define P_W2   8388608
#define P_W3   9437184
__global__ void __launch_bounds__(256)
prep_k(const float4* __restrict__ m0, const float4* __restrict__ s0,
       const float4* __restrict__ s1,
       const float4* __restrict__ wq, const float4* __restrict__ wk,
       const float4* __restrict__ wv, const float4* __restrict__ wo,
       const float4* __restrict__ w1, const float4* __restrict__ w2,
       const float4* __restrict__ w3,
       ushort4* __restrict__ m0b, ushort4* __restrict__ s0b,
       ushort4* __restrict__ evo,
       ushort4* __restrict__ wqb, ushort4* __restrict__ wkb,
       ushort4* __restrict__ wvb, ushort4* __restrict__ wob,
       ushort4* __restrict__ w1b, ushort4* __restrict__ w2b,
       ushort4* __restrict__ w3b)
{
  const int stride = gridDim.x * 256;
  for (int i = blockIdx.x * 256 + threadIdx.x; i < P_W3; i += stride) {
    if (i < P_M0) {
      m0b[i] = cvt4(m0[i]);
    } else if (i < P_S0) {
      int j = i - P_M0; s0b[j] = cvt4(s0[j]);
    } else if (i < P_EVO) {
      int j = i - P_S0;
      float4 a = s0[j], b = s1[j];
      float4 d; d.x = b.x - a.x; d.y = b.y - a.y; d.z = b.z - a.z; d.w = b.w - a.w;
      evo[j] = cvt4(d);
    } else if (i < P_WQ) {
      int j = i - P_EVO; wqb[j] = cvt4(wq[j]);
    } else if (i < P_WK) {
      int j = i - P_WQ; wkb[j] = cvt4(wk[j]);
    } else if (i < P_WV) {
      int j = i - P_WK; wvb[j] = cvt4(wv[j]);
    } else if (i < P_WO) {
      int j = i - P_WV; wob[j] = cvt4(wo[j]);
    } else if (i < P_W1) {
      int j = i - P_WO; w1b[j] = cvt4(w1[j]);
    } else if (i < P_W2) {
      int j = i - P_W1; w2b[j] = cvt4(w2[j]);
    } else {
      int j = i - P_W2; w3b[j] = cvt4(w3[j]);
    }
  }
}

// 1/||stored_morph0_n|| in fp64 (used by approx top-k scale and fp64 refine)
__global__ void rnormd_k(const float* __restrict__ s0, double* __restrict__ rnd) {
  __shared__ double red[256];
  int n = blockIdx.x, tid = threadIdx.x;
  const float4* row = (const float4*)(s0 + (size_t)n * DD);
  float4 x = row[tid];
  double ss = (double)x.x * x.x + (double)x.y * x.y + (double)x.z * x.z + (double)x.w * x.w;
  red[tid] = ss; __syncthreads();
  for (int s = 128; s > 0; s >>= 1) {
    if (tid < s) red[tid] += red[tid + s];
    __syncthreads();
  }
  if (tid == 0) rnd[n] = 1.0 / fmax(sqrt(red[0]), 1e-12);
}

// ------- bf16 MFMA GEMM, 2-phase LDS double buffer: C = epi(A[M,K] @ Bw[N,K]^T) -------
// (used for the skinny/medium GEMMs where a 256^2 grid would under-fill the GPU)
template<bool RELU, bool RESID, bool OUTBF16>
__global__ void __launch_bounds__(256)
gemm_bt(const bf16_t* __restrict__ A, const bf16_t* __restrict__ Bw,
        const float* __restrict__ bias, const float* __restrict__ resid,
        float* __restrict__ outf, bf16_t* __restrict__ outb,
        int M, int Nn, int Kk)
{
  __shared__ alignas(16) bf16_t At[2][4096];   // [buf][128 rows][32 k]
  __shared__ alignas(16) bf16_t Bt[2][4096];
  const int tid = threadIdx.x;
  const int wave = tid >> 6, lane = tid & 63;
  const int wm = wave >> 1, wn = wave & 1;
  const int bm = blockIdx.y << 7, bn = blockIdx.x << 7;

  const int srow  = (wave << 4) + (lane >> 2);   // 0..63
  const int scolb = (lane & 3) << 4;             // 0,16,32,48
  const char* pA0 = (const char*)A  + (size_t)(bm + srow) * Kk * 2 + scolb;
  const char* pA1 = (const char*)A  + (size_t)(bm + srow + 64) * Kk * 2 + scolb;
  const char* pB0 = (const char*)Bw + (size_t)(bn + srow) * Kk * 2 + scolb;
  const char* pB1 = (const char*)Bw + (size_t)(bn + srow + 64) * Kk * 2 + scolb;

  f32x4 zero = {0.f, 0.f, 0.f, 0.f};
  f32x4 acc[4][4];
  #pragma unroll
  for (int i = 0; i < 4; ++i)
    #pragma unroll
    for (int j = 0; j < 4; ++j) acc[i][j] = zero;

  const int fAoff = ((wm << 6) + (lane & 15)) * 32 + ((lane >> 4) << 3);
  const int fBoff = ((wn << 6) + (lane & 15)) * 32 + ((lane >> 4) << 3);

  const int nt = Kk >> 5;
  {
    char* lA = (char*)At[0] + (wave << 10);
    char* lB = (char*)Bt[0] + (wave << 10);
    gload_lds16(pA0, lA);
    gload_lds16(pA1, lA + 4096);
    gload_lds16(pB0, lB);
    gload_lds16(pB1, lB + 4096);
  }
  __syncthreads();

  for (int t = 0; t < nt; ++t) {
    const int cur = t & 1;
    if (t + 1 < nt) {
      size_t kb = (size_t)(t + 1) << 6;          // 64 bytes per K-step
      char* lA = (char*)At[cur ^ 1] + (wave << 10);
      char* lB = (char*)Bt[cur ^ 1] + (wave << 10);
      gload_lds16(pA0 + kb, lA);
      gload_lds16(pA1 + kb, lA + 4096);
      gload_lds16(pB0 + kb, lB);
      gload_lds16(pB1 + kb, lB + 4096);
    }
    bf16x8 av[4], bv[4];
    #pragma unroll
    for (int i = 0; i < 4; ++i) av[i] = *(const bf16x8*)(&At[cur][fAoff + i * 512]);
    #pragma unroll
    for (int j = 0; j < 4; ++j) bv[j] = *(const bf16x8*)(&Bt[cur][fBoff + j * 512]);
    #pragma unroll
    for (int i = 0; i < 4; ++i)
      #pragma unroll
      for (int j = 0; j < 4; ++j)
        acc[i][j] = __builtin_amdgcn_mfma_f32_16x16x32_bf16(av[i], bv[j], acc[i][j], 0, 0, 0);
    __syncthreads();
  }

  const int r0 = bm + (wm << 6) + ((lane >> 4) << 2);
  const int c0 = bn + (wn << 6) + (lane & 15);
  #pragma unroll
  for (int i = 0; i < 4; ++i) {
    #pragma unroll
    for (int j = 0; j < 4; ++j) {
      #pragma unroll
      for (int r = 0; r < 4; ++r) {
        int row = r0 + i * 16 + r;
        int col = c0 + j * 16;
        size_t o = (size_t)row * Nn + col;
        float v = acc[i][j][r];
        if (bias)  v += bias[col];
        if (RESID) v += resid[o];
        if (RELU)  v = fmaxf(v, 0.f);
        if (OUTBF16) outb[o] = (bf16_t)v;
        else         outf[o] = v;
      }
    }
  }
}

// ------- 256x256x64 8-wave MFMA GEMM, single-read fragment schedule (T3+T4) -----
// C[M,N] = epi(A[M,K] @ Bw[N,K]^T + bias); bf16 out. M%256==0, N%256==0, K%64==0.
// LDS: 2 dbuf x (A 256x64 + B 256x64) bf16 = 128 KiB. XOR swizzle slot^=(row&7) on reads,
// inverse-applied to the per-lane global source of global_load_lds (rule #21).
// Phases by (kk, m-half) so EVERY fragment is read exactly once per K-tile:
//   P1{avL(mh0,kk0)+bv(kk0): 8 rd, 16 MFMA} P2{av(mh1,kk0): 4 rd} P3{kk1 +bv(kk1): 8} P4{4}
// = 24 ds_read_b128/wave/K-tile (was 40 -> LDS-BW was the R5 limiter).
// Stage issue order: sB0@P1 sB1@P2 sA0@P3 sA1@P4 (B fully lands before P1 reads all wn rows).
// Gates: vmcnt(2) end-P4 (covers sB0,sB1,sA0 of t+1 for P1) and end-P1 (covers sA1(t) for P2);
// per-wave vmcnt + s_barrier after the wait => cross-wave valid.
template<bool RELU>
__global__ void __launch_bounds__(512, 2)
gemm8p(const bf16_t* __restrict__ A, const bf16_t* __restrict__ Bw,
       const float* __restrict__ bias, bf16_t* __restrict__ outb,
       int Nn, int Kk, int nbx)
{
  __shared__ alignas(16) bf16_t As[2][16384];
  __shared__ alignas(16) bf16_t Bs[2][16384];
  const int tid  = threadIdx.x;
  const int lane = tid & 63, wv = tid >> 6;
  const int wm = wv >> 2, wn = wv & 3;          // 2 x 4 waves
  const int ln15 = lane & 15, ln4 = lane >> 4;

  // bijective XCD swizzle (m204)
  const int nwg = gridDim.x;
  const int q = nwg >> 3, r = nwg & 7;
  const int xcd = blockIdx.x & 7, loc = blockIdx.x >> 3;
  const int swz = (xcd < r ? xcd * (q + 1) : r * (q + 1) + (xcd - r) * q) + loc;
  const int bm = (swz / nbx) << 8;
  const int bn = (swz % nbx) << 8;

  const int NT = Kk >> 6;

  f32x4 acc[8][4];
  f32x4 zero = {0.f, 0.f, 0.f, 0.f};
  #pragma unroll
  for (int i = 0; i < 8; ++i)
    #pragma unroll
    for (int j = 0; j < 4; ++j) acc[i][j] = zero;

  // stage A region MH of tile kt: rows [MH*64,+64) u [128+MH*64,+64); 2 issues
  auto stageA = [&](int MH, bf16_t* lds, int kt) {
    #pragma unroll
    for (int u = 0; u < 2; ++u) {
      int rowbase = u * 128 + MH * 64 + wv * 8;
      int row = rowbase + (lane >> 3);
      int slot = (lane & 7) ^ (row & 7);
      gload_lds16(A + (size_t)(bm + row) * Kk + kt * 64 + slot * 8,
                  (char*)lds + rowbase * 128);
    }
  };
  // stage B region NH (rows with bit5==NH): 2 issues
  auto stageB = [&](int NH, bf16_t* lds, int kt) {
    #pragma unroll
    for (int u = 0; u < 2; ++u) {
      int rowbase = u * 128 + ((wv >> 2) << 6) + NH * 32 + ((wv & 3) << 3);
      int row = rowbase + (lane >> 3);
      int slot = (lane & 7) ^ (row & 7);
      gload_lds16(Bw + (size_t)(bn + row) * Kk + kt * 64 + slot * 8,
                  (char*)lds + rowbase * 128);
    }
  };

  // prologue: full tile 0, hard drain
  stageA(0, As[0], 0); stageA(1, As[0], 0);
  stageB(0, Bs[0], 0); stageB(1, Bs[0], 0);
  asm volatile("s_waitcnt vmcnt(0)" ::: "memory");
  __builtin_amdgcn_s_barrier();

#define DS_A(MH, KK)                                                             \
    _Pragma("unroll") for (int mi = 0; mi < 4; ++mi) {                           \
      const int row = wm * 128 + (MH) * 64 + mi * 16 + ln15;                     \
      const int slot = (KK) * 4 + ln4;                                           \
      av[mi] = *(const bf16x8*)(Ab + row * 128 + ((slot ^ (row & 7)) << 4));     \
    }
#define DS_B(KK)                                                                 \
    _Pragma("unroll") for (int nj = 0; nj < 4; ++nj) {                           \
      const int row = wn * 64 + nj * 16 + ln15;                                  \
      const int slot = (KK) * 4 + ln4;                                           \
      bv[nj] = *(const bf16x8*)(Bb + row * 128 + ((slot ^ (row & 7)) << 4));     \
    }
#define MMA(MH)                                                                  \
    __builtin_amdgcn_s_setprio(1);                                               \
    _Pragma("unroll") for (int mi = 0; mi < 4; ++mi)                             \
      _Pragma("unroll") for (int nj = 0; nj < 4; ++nj)                           \
        acc[(MH)*4+mi][nj] = __builtin_amdgcn_mfma_f32_16x16x32_bf16(            \
            av[mi], bv[nj], acc[(MH)*4+mi][nj], 0, 0, 0);                        \
    __builtin_amdgcn_s_setprio(0);
#define VMW2                                                                     \
    asm volatile("s_waitcnt vmcnt(2)" ::: "memory");                             \
    __builtin_amdgcn_sched_barrier(0);

  for (int t = 0; t < NT; ++t) {
    const int cur = t & 1;
    const char* Ab = (const char*)As[cur];
    const char* Bb = (const char*)Bs[cur];
    bf16_t* nA = As[cur ^ 1];
    bf16_t* nB = Bs[cur ^ 1];
    const bool more = (t + 1 < NT);
    bf16x8 av[4], bv[4];

    // P1: kk0 mh0 (reads A0 + ALL B rows kk0); stage sB0(t+1); gate: sA1(t) landed for P2
    DS_A(0, 0); DS_B(0);
    if (more) stageB(0, nB, t + 1);
    __builtin_amdgcn_s_barrier();
    MMA(0);
    VMW2;
    __builtin_amdgcn_s_barrier();

    // P2: kk0 mh1 (bv reused in regs); stage sB1(t+1)
    DS_A(1, 0);
    if (more) stageB(1, nB, t + 1);
    __builtin_amdgcn_s_barrier();
    MMA(1);
    __builtin_amdgcn_s_barrier();

    // P3: kk1 mh0 + bv(kk1); stage sA0(t+1)
    DS_A(0, 1); DS_B(1);
    if (more) stageA(0, nA, t + 1);
    __builtin_amdgcn_s_barrier();
    MMA(0);
    __builtin_amdgcn_s_barrier();

    // P4: kk1 mh1; stage sA1(t+1); gate: sB0,sB1,sA0(t+1) landed for next P1
    DS_A(1, 1);
    if (more) stageA(1, nA, t + 1);
    __builtin_amdgcn_s_barrier();
    MMA(1);
    VMW2;
    __builtin_amdgcn_s_barrier();
  }
#undef DS_A
#undef DS_B
#undef MMA
#undef VMW2

  // epilogue: C/D layout col=lane&15, row=(lane>>4)*4+reg
  #pragma unroll
  for (int am = 0; am < 8; ++am) {
    #pragma unroll
    for (int an = 0; an < 4; ++an) {
      #pragma unroll
      for (int rr = 0; rr < 4; ++rr) {
        int row = bm + wm * 128 + am * 16 + (lane >> 4) * 4 + rr;
        int col = bn + wn * 64 + an * 16 + ln15;
        float v = acc[am][an][rr] + bias[col];
        if (RELU) v = fmaxf(v, 0.f);
        outb[(size_t)row * Nn + col] = (bf16_t)v;
      }
    }
  }
}

// ---------------- approx top-8 per row ----------------
__global__ void __launch_bounds__(256)
topk8_k(const float* __restrict__ sim, const double* __restrict__ rnd,
        int* __restrict__ cand)
{
  __shared__ float vals[NN];
  __shared__ float rv[256];
  __shared__ int   ri[256];
  int b = blockIdx.x, tid = threadIdx.x;
  for (int t = 0; t < NN / 256; ++t) {
    int i = tid + t * 256;
    vals[i] = sim[(size_t)b * NN + i] * (float)rnd[i];
  }
  __syncthreads();
  for (int p = 0; p < 8; ++p) {
    float bvv = -INFINITY; int bi = NN;
    for (int t = 0; t < NN / 256; ++t) {
      int i = tid + t * 256;
      float v = vals[i];
      if (v > bvv) { bvv = v; bi = i; }   // strict > keeps lowest index
    }
    rv[tid] = bvv; ri[tid] = bi;
    __syncthreads();
    for (int s = 128; s > 0; s >>= 1) {
      if (tid < s) {
        float v2 = rv[tid + s]; int i2 = ri[tid + s];
        if (v2 > rv[tid] || (v2 == rv[tid] && i2 < ri[tid])) { rv[tid] = v2; ri[tid] = i2; }
      }
      __syncthreads();
    }
    if (tid == 0) {
      int wsel = ri[0];
      cand[b * 8 + p] = wsel;
      vals[wsel] = -INFINITY;
    }
    __syncthreads();
  }
}

// ---------------- fp64 re-rank of the 8 candidates -> exact top-5 ----------------
__global__ void __launch_bounds__(256)
refine_k(const float* __restrict__ m0, const float* __restrict__ s0,
         const double* __restrict__ rnd, const int* __restrict__ cand,
         int* __restrict__ topidx)
{
  __shared__ double red[256];
  __shared__ double vals[8];
  int b = blockIdx.x, tid = threadIdx.x;
  int cs[8];
  #pragma unroll
  for (int j = 0; j < 8; ++j) cs[j] = cand[b * 8 + j];
  const float* q = m0 + (size_t)b * DD;
  double part[8];
  #pragma unroll
  for (int j = 0; j < 8; ++j) part[j] = 0.0;
  for (int d = tid; d < DD; d += 256) {
    double qd = (double)q[d];
    #pragma unroll
    for (int j = 0; j < 8; ++j)
      part[j] += qd * (double)s0[(size_t)cs[j] * DD + d];
  }
  for (int j = 0; j < 8; ++j) {
    red[tid] = part[j]; __syncthreads();
    for (int s = 128; s > 0; s >>= 1) {
      if (tid < s) red[tid] += red[tid + s];
      __syncthreads();
    }
    if (tid == 0) vals[j] = red[0] * rnd[cs[j]];
    __syncthreads();
  }
  if (tid == 0) {
    bool used[8] = {false,false,false,false,false,false,false,false};
    for (int p = 0; p < KSEL; ++p) {
      int best = -1;
      for (int j = 0; j < 8; ++j) {
        if (used[j]) continue;
        if (best < 0 || vals[j] > vals[best] ||
            (vals[j] == vals[best] && cs[j] < cs[best])) best = j;
      }
      used[best] = true;
      topidx[b * KSEL + p] = cs[best];
    }
  }
}

// ---- fused attention: scores from eK gather; ctx[d] = sum_j a_{head(d),j} * eV[idx_j][d] ----
__global__ void __launch_bounds__(256)
attn_k(const bf16_t* __restrict__ q, const bf16_t* __restrict__ eK,
       const bf16_t* __restrict__ eV, const int* __restrict__ tidx,
       bf16_t* __restrict__ ctx, float* __restrict__ attn_out)
{
  __shared__ float aw[NHEAD][KSEL];
  const int b = blockIdx.x, t = threadIdx.x;
  const int d0 = t << 2;                 // 4 dims per thread; head = t>>5
  int idx[KSEL];
  #pragma unroll
  for (int j = 0; j < KSEL; ++j) idx[j] = tidx[b * KSEL + j];

  bf16x4 qv = *(const bf16x4*)(q + (size_t)b * DD + d0);
  float s[KSEL];
  #pragma unroll
  for (int j = 0; j < KSEL; ++j) {
    bf16x4 kv = *(const bf16x4*)(eK + (size_t)idx[j] * DD + d0);
    float p = (float)qv[0] * (float)kv[0] + (float)qv[1] * (float)kv[1]
            + (float)qv[2] * (float)kv[2] + (float)qv[3] * (float)kv[3];
    #pragma unroll
    for (int m = 16; m > 0; m >>= 1) p += __shfl_xor(p, m);  // reduce 32-thread head group
    s[j] = p * 0.08838834764831845f;     // 1/sqrt(128)
  }
  float mx = s[0];
  #pragma unroll
  for (int j = 1; j < KSEL; ++j) mx = fmaxf(mx, s[j]);
  float e[KSEL], sum = 0.f;
  #pragma unroll
  for (int j = 0; j < KSEL; ++j) { e[j] = expf(s[j] - mx); sum += e[j]; }
  float inv = 1.f / sum;

  float c0 = 0.f, c1 = 0.f, c2 = 0.f, c3 = 0.f;
  #pragma unroll
  for (int j = 0; j < KSEL; ++j) {
    float a = e[j] * inv;
    bf16x4 vv = *(const bf16x4*)(eV + (size_t)idx[j] * DD + d0);
    c0 += a * (float)vv[0]; c1 += a * (float)vv[1];
    c2 += a * (float)vv[2]; c3 += a * (float)vv[3];
    if ((t & 31) == 0) aw[t >> 5][j] = a;
  }
  bf16x4 co; co[0] = (bf16_t)c0; co[1] = (bf16_t)c1; co[2] = (bf16_t)c2; co[3] = (bf16_t)c3;
  *(bf16x4*)(ctx + (size_t)b * DD + d0) = co;
  __syncthreads();
  if (t < KSEL) {
    float m = 0.f;
    #pragma unroll
    for (int hh = 0; hh < NHEAD; ++hh) m += aw[hh][t];
    attn_out[(size_t)b * KSEL + t] = m * 0.125f;
  }
}

// ---------------- launch ----------------
extern "C" void kernel_launch(void* const* d_in, const int* in_sizes, int n_in,
                              void* d_out, int out_size, void* d_ws, size_t ws_size,
                              hipStream_t stream) {
  (void)in_sizes; (void)n_in; (void)out_size; (void)ws_size;
  const float* morph0 = (const float*)d_in[0];
  const float* s0     = (const float*)d_in[1];
  const float* s1     = (const float*)d_in[2];
  const float* wq = (const float*)d_in[3];  const float* bq = (const float*)d_in[4];
  const float* wk = (const float*)d_in[5];  const float* bk = (const float*)d_in[6];
  const float* wv = (const float*)d_in[7];  const float* bv = (const float*)d_in[8];
  const float* wo = (const float*)d_in[9];  const float* bo = (const float*)d_in[10];
  const float* w1 = (const float*)d_in[11]; const float* b1 = (const float*)d_in[12];
  const float* w2 = (const float*)d_in[13]; const float* b2 = (const float*)d_in[14];
  const float* w3 = (const float*)d_in[15]; const float* b3 = (const float*)d_in[16];

  char* ws = (char*)d_ws;
  size_t off = 0;
  auto alloc = [&](size_t bytes) { char* p = ws + off; off += (bytes + 255) & ~(size_t)255; return p; };

  float*  sim  = (float*) alloc((size_t)BB * NN * 4);     // 33.5MB, reused as h1 (bf16) later
  bf16_t* m0b  = (bf16_t*)alloc((size_t)BB * DD * 2);
  bf16_t* s0b  = (bf16_t*)alloc((size_t)NN * DD * 2);
  bf16_t* evo  = (bf16_t*)alloc((size_t)NN * DD * 2);
  double* rnd  = (double*)alloc((size_t)NN * 8);
  int*    cand = (int*)   alloc((size_t)BB * 8 * 4);
  int*    tidx = (int*)   alloc((size_t)BB * KSEL * 4);
  bf16_t* qb   = (bf16_t*)alloc((size_t)BB * DD * 2);
  bf16_t* eKb  = (bf16_t*)alloc((size_t)NN * DD * 2);
  bf16_t* eVb  = (bf16_t*)alloc((size_t)NN * DD * 2);
  bf16_t* ctxb = (bf16_t*)alloc((size_t)BB * DD * 2);
  bf16_t* xb   = (bf16_t*)alloc((size_t)BB * DD * 2);
  bf16_t* wqb  = (bf16_t*)alloc((size_t)DD * DD * 2);
  bf16_t* wkb  = (bf16_t*)alloc((size_t)DD * DD * 2);
  bf16_t* wvb  = (bf16_t*)alloc((size_t)DD * DD * 2);
  bf16_t* wob  = (bf16_t*)alloc((size_t)DD * DD * 2);
  bf16_t* w1b  = (bf16_t*)alloc((size_t)HH * DD * 2);
  bf16_t* w2b  = (bf16_t*)alloc((size_t)HH * HH * 2);
  bf16_t* w3b  = (bf16_t*)alloc((size_t)DD * HH * 2);
  bf16_t* h2b  = (bf16_t*)alloc((size_t)BB * HH * 2);
  bf16_t* h1b  = (bf16_t*)sim;  // alias: sim dead after topk; sizes match (33.5MB)
  float*  attn_out = (float*)d_out + (size_t)BB * DD;

  // fused prep: all fp32->bf16 conversions + evo in one launch
  prep_k<<<dim3(2048), dim3(256), 0, stream>>>(
      (const float4*)morph0, (const float4*)s0, (const float4*)s1,
      (const float4*)wq, (const float4*)wk, (const float4*)wv, (const float4*)wo,
      (const float4*)w1, (const float4*)w2, (const float4*)w3,
      (ushort4*)m0b, (ushort4*)s0b, (ushort4*)evo,
      (ushort4*)wqb, (ushort4*)wkb, (ushort4*)wvb, (ushort4*)wob,
      (ushort4*)w1b, (ushort4*)w2b, (ushort4*)w3b);
  rnormd_k<<<dim3(NN), dim3(256), 0, stream>>>(s0, rnd);

  // retrieval
  gemm_bt<false,false,false><<<dim3(NN/128, BB/128), dim3(256), 0, stream>>>(
      m0b, s0b, nullptr, nullptr, sim, nullptr, BB, NN, DD);
  topk8_k<<<dim3(BB), dim3(256), 0, stream>>>(sim, rnd, cand);
  refine_k<<<dim3(BB), dim3(256), 0, stream>>>(morph0, s0, rnd, cand, tidx);

  // projections on the 2048 unique evo rows (gather commutes with row-GEMM)
  gemm_bt<false,false,true><<<dim3(DD/128, BB/128), dim3(256), 0, stream>>>(
      m0b, wqb, bq, nullptr, nullptr, qb, BB, DD, DD);
  gemm_bt<false,false,true><<<dim3(DD/128, NN/128), dim3(256), 0, stream>>>(
      evo, wkb, bk, nullptr, nullptr, eKb, NN, DD, DD);
  gemm_bt<false,false,true><<<dim3(DD/128, NN/128), dim3(256), 0, stream>>>(
      evo, wvb, bv, nullptr, nullptr, eVb, NN, DD, DD);

  // fused attention: scores, softmax, ctx (per-head weights in value space); attn_weights out
  attn_k<<<dim3(BB), dim3(256), 0, stream>>>(qb, eKb, eVb, tidx, ctxb, attn_out);

  // out-proj + residual -> x
  gemm_bt<false,true,true><<<dim3(DD/128, BB/128), dim3(256), 0, stream>>>(
      ctxb, wob, bo, morph0, nullptr, xb, BB, DD, DD);

  // MLP: big square GEMMs on the single-read 256^2 kernel
  gemm8p<true><<<dim3((BB/256)*(HH/256)), dim3(512), 0, stream>>>(
      xb, w1b, b1, h1b, HH, DD, HH/256);
  gemm8p<true><<<dim3((BB/256)*(HH/256)), dim3(512), 0, stream>>>(
      h1b, w2b, b2, h2b, HH, HH, HH/256);
  gemm_bt<false,true,false><<<dim3(DD/128, BB/128), dim3(256), 0, stream>>>(
      h2b, w3b, b3, morph0, (float*)d_out, nullptr, BB, DD, HH);
}

// Round 7
// 514.056 us; speedup vs baseline: 1.5947x; 1.0389x over previous
//
#include <hip/hip_runtime.h>
#include <hip/hip_bf16.h>
#include <math.h>

typedef __bf16 bf16_t;
typedef __bf16 bf16x4 __attribute__((ext_vector_type(4)));
typedef __bf16 bf16x8 __attribute__((ext_vector_type(8)));
typedef float  f32x4  __attribute__((ext_vector_type(4)));

#define BB 4096
#define NN 2048
#define DD 1024
#define HH 4096
#define KSEL 5
#define NHEAD 8

__device__ __forceinline__ unsigned short bfbits(float f) {
  return __builtin_bit_cast(unsigned short, (bf16_t)f);
}

__device__ __forceinline__ void gload_lds16(const void* g, void* l) {
  __builtin_amdgcn_global_load_lds(
      (const __attribute__((address_space(1))) void*)g,
      (__attribute__((address_space(3))) void*)l, 16, 0, 0);
}

__device__ __forceinline__ ushort4 cvt4(float4 x) {
  ushort4 o;
  o.x = bfbits(x.x); o.y = bfbits(x.y); o.z = bfbits(x.z); o.w = bfbits(x.w);
  return o;
}

// ---------------- fused fp32->bf16 prep (all conversions in one launch) ----------------
// segments (float4 units, cumulative):
#define P_M0   1048576
#define P_S0   1572864
#define P_EVO  2097152
#define P_WQ   2359296
#define P_WKV  2883584
#define P_WO   3145728
#define P_W1   4194304
#define P_W2   8388608
#define P_W3   9437184
#define P_BKV  9437696
__global__ void __launch_bounds__(256)
prep_k(const float4* __restrict__ m0, const float4* __restrict__ s0,
       const float4* __restrict__ s1,
       const float4* __restrict__ wq, const float4* __restrict__ wk,
       const float4* __restrict__ wv, const float4* __restrict__ wo,
       const float4* __restrict__ w1, const float4* __restrict__ w2,
       const float4* __restrict__ w3,
       const float4* __restrict__ bk, const float4* __restrict__ bv,
       ushort4* __restrict__ m0b, ushort4* __restrict__ s0b,
       ushort4* __restrict__ evo,
       ushort4* __restrict__ wqb, ushort4* __restrict__ wkvb,
       ushort4* __restrict__ wob,
       ushort4* __restrict__ w1b, ushort4* __restrict__ w2b,
       ushort4* __restrict__ w3b, float4* __restrict__ bkv)
{
  const int stride = gridDim.x * 256;
  for (int i = blockIdx.x * 256 + threadIdx.x; i < P_BKV; i += stride) {
    if (i < P_M0) {
      m0b[i] = cvt4(m0[i]);
    } else if (i < P_S0) {
      int j = i - P_M0; s0b[j] = cvt4(s0[j]);
    } else if (i < P_EVO) {
      int j = i - P_S0;
      float4 a = s0[j], b = s1[j];
      float4 d; d.x = b.x - a.x; d.y = b.y - a.y; d.z = b.z - a.z; d.w = b.w - a.w;
      evo[j] = cvt4(d);
    } else if (i < P_WQ) {
      int j = i - P_EVO; wqb[j] = cvt4(wq[j]);
    } else if (i < P_WKV) {
      int j = i - P_WQ;                       // 0..524287: first wk block, then wv
      wkvb[j] = cvt4(j < 262144 ? wk[j] : wv[j - 262144]);
    } else if (i < P_WO) {
      int j = i - P_WKV; wob[j] = cvt4(wo[j]);
    } else if (i < P_W1) {
      int j = i - P_WO; w1b[j] = cvt4(w1[j]);
    } else if (i < P_W2) {
      int j = i - P_W1; w2b[j] = cvt4(w2[j]);
    } else if (i < P_W3) {
      int j = i - P_W2; w3b[j] = cvt4(w3[j]);
    } else {
      int j = i - P_W3;                       // 0..511 float4 = concat(bk,bv)
      bkv[j] = (j < 256) ? bk[j] : bv[j - 256];
    }
  }
}

// 1/||stored_morph0_n|| in fp64 (used by approx top-k scale and fp64 refine)
__global__ void rnormd_k(const float* __restrict__ s0, double* __restrict__ rnd) {
  __shared__ double red[256];
  int n = blockIdx.x, tid = threadIdx.x;
  const float4* row = (const float4*)(s0 + (size_t)n * DD);
  float4 x = row[tid];
  double ss = (double)x.x * x.x + (double)x.y * x.y + (double)x.z * x.z + (double)x.w * x.w;
  red[tid] = ss; __syncthreads();
  for (int s = 128; s > 0; s >>= 1) {
    if (tid < s) red[tid] += red[tid + s];
    __syncthreads();
  }
  if (tid == 0) rnd[n] = 1.0 / fmax(sqrt(red[0]), 1e-12);
}

// ------- bf16 MFMA GEMM, 2-phase LDS double buffer: C = epi(A[M,K] @ Bw[N,K]^T) -------
template<bool RELU, bool RESID, bool OUTBF16>
__global__ void __launch_bounds__(256)
gemm_bt(const bf16_t* __restrict__ A, const bf16_t* __restrict__ Bw,
        const float* __restrict__ bias, const float* __restrict__ resid,
        float* __restrict__ outf, bf16_t* __restrict__ outb,
        int M, int Nn, int Kk)
{
  __shared__ alignas(16) bf16_t At[2][4096];   // [buf][128 rows][32 k]
  __shared__ alignas(16) bf16_t Bt[2][4096];
  const int tid = threadIdx.x;
  const int wave = tid >> 6, lane = tid & 63;
  const int wm = wave >> 1, wn = wave & 1;
  const int bm = blockIdx.y << 7, bn = blockIdx.x << 7;

  const int srow  = (wave << 4) + (lane >> 2);   // 0..63
  const int scolb = (lane & 3) << 4;             // 0,16,32,48
  const char* pA0 = (const char*)A  + (size_t)(bm + srow) * Kk * 2 + scolb;
  const char* pA1 = (const char*)A  + (size_t)(bm + srow + 64) * Kk * 2 + scolb;
  const char* pB0 = (const char*)Bw + (size_t)(bn + srow) * Kk * 2 + scolb;
  const char* pB1 = (const char*)Bw + (size_t)(bn + srow + 64) * Kk * 2 + scolb;

  f32x4 zero = {0.f, 0.f, 0.f, 0.f};
  f32x4 acc[4][4];
  #pragma unroll
  for (int i = 0; i < 4; ++i)
    #pragma unroll
    for (int j = 0; j < 4; ++j) acc[i][j] = zero;

  const int fAoff = ((wm << 6) + (lane & 15)) * 32 + ((lane >> 4) << 3);
  const int fBoff = ((wn << 6) + (lane & 15)) * 32 + ((lane >> 4) << 3);

  const int nt = Kk >> 5;
  {
    char* lA = (char*)At[0] + (wave << 10);
    char* lB = (char*)Bt[0] + (wave << 10);
    gload_lds16(pA0, lA);
    gload_lds16(pA1, lA + 4096);
    gload_lds16(pB0, lB);
    gload_lds16(pB1, lB + 4096);
  }
  __syncthreads();

  for (int t = 0; t < nt; ++t) {
    const int cur = t & 1;
    if (t + 1 < nt) {
      size_t kb = (size_t)(t + 1) << 6;          // 64 bytes per K-step
      char* lA = (char*)At[cur ^ 1] + (wave << 10);
      char* lB = (char*)Bt[cur ^ 1] + (wave << 10);
      gload_lds16(pA0 + kb, lA);
      gload_lds16(pA1 + kb, lA + 4096);
      gload_lds16(pB0 + kb, lB);
      gload_lds16(pB1 + kb, lB + 4096);
    }
    bf16x8 av[4], bv[4];
    #pragma unroll
    for (int i = 0; i < 4; ++i) av[i] = *(const bf16x8*)(&At[cur][fAoff + i * 512]);
    #pragma unroll
    for (int j = 0; j < 4; ++j) bv[j] = *(const bf16x8*)(&Bt[cur][fBoff + j * 512]);
    #pragma unroll
    for (int i = 0; i < 4; ++i)
      #pragma unroll
      for (int j = 0; j < 4; ++j)
        acc[i][j] = __builtin_amdgcn_mfma_f32_16x16x32_bf16(av[i], bv[j], acc[i][j], 0, 0, 0);
    __syncthreads();
  }

  const int r0 = bm + (wm << 6) + ((lane >> 4) << 2);
  const int c0 = bn + (wn << 6) + (lane & 15);
  #pragma unroll
  for (int i = 0; i < 4; ++i) {
    #pragma unroll
    for (int j = 0; j < 4; ++j) {
      #pragma unroll
      for (int r = 0; r < 4; ++r) {
        int row = r0 + i * 16 + r;
        int col = c0 + j * 16;
        size_t o = (size_t)row * Nn + col;
        float v = acc[i][j][r];
        if (bias)  v += bias[col];
        if (RESID) v += resid[o];
        if (RELU)  v = fmaxf(v, 0.f);
        if (OUTBF16) outb[o] = (bf16_t)v;
        else         outf[o] = v;
      }
    }
  }
}

// ------- 256x256x64 8-wave MFMA GEMM, barrier-light interleaved pipeline -----
// C[M,N] = epi(A[M,K] @ Bw[N,K]^T + bias); bf16 out. M%256==0, N%256==0, K%64==0.
// LDS: 2 dbuf x (A 256x64 + B 256x64) bf16 = 128 KiB. XOR swizzle slot^=(row&7) on reads,
// inverse-applied to the per-lane global source of global_load_lds (rule #21).
// ONE barrier per K-tile. Correctness:
//  - within tile t: ds_reads hit buf[cur], stages write buf[cur^1] -> disjoint, no sync needed.
//  - tile boundary: every wave does vmcnt(0) (its stages landed) then s_barrier -> all waves'
//    stages of t+1 visible before any wave reads them.
//  - reads of buf[cur] retire before each wave's barrier arrival (consumed by its MFMAs),
//    so t+1's stages into that buffer cannot overtake them.
// Interleave: reads for MFMA cluster p+1 are issued before cluster p so the LDS pipe runs
// concurrently with the MFMA pipe (waves desync within the tile). Compiler inserts minimal
// lgkmcnt for the register deps (m97 evidence); WAR reg reuse is dep-tracked.
template<bool RELU>
__global__ void __launch_bounds__(512, 2)
gemm8p(const bf16_t* __restrict__ A, const bf16_t* __restrict__ Bw,
       const float* __restrict__ bias, bf16_t* __restrict__ outb,
       int Nn, int Kk, int nbx)
{
  __shared__ alignas(16) bf16_t As[2][16384];
  __shared__ alignas(16) bf16_t Bs[2][16384];
  const int tid  = threadIdx.x;
  const int lane = tid & 63, wv = tid >> 6;
  const int wm = wv >> 2, wn = wv & 3;          // 2 x 4 waves
  const int ln15 = lane & 15, ln4 = lane >> 4;

  // bijective XCD swizzle (m204)
  const int nwg = gridDim.x;
  const int q = nwg >> 3, r = nwg & 7;
  const int xcd = blockIdx.x & 7, loc = blockIdx.x >> 3;
  const int swz = (xcd < r ? xcd * (q + 1) : r * (q + 1) + (xcd - r) * q) + loc;
  const int bm = (swz / nbx) << 8;
  const int bn = (swz % nbx) << 8;

  const int NT = Kk >> 6;

  f32x4 acc[8][4];
  f32x4 zero = {0.f, 0.f, 0.f, 0.f};
  #pragma unroll
  for (int i = 0; i < 8; ++i)
    #pragma unroll
    for (int j = 0; j < 4; ++j) acc[i][j] = zero;

  // stage A region MH of tile kt: rows [MH*64,+64) u [128+MH*64,+64); 2 issues
  auto stageA = [&](int MH, bf16_t* lds, int kt) {
    #pragma unroll
    for (int u = 0; u < 2; ++u) {
      int rowbase = u * 128 + MH * 64 + wv * 8;
      int row = rowbase + (lane >> 3);
      int slot = (lane & 7) ^ (row & 7);
      gload_lds16(A + (size_t)(bm + row) * Kk + kt * 64 + slot * 8,
                  (char*)lds + rowbase * 128);
    }
  };
  // stage B region NH (rows with bit5==NH): 2 issues
  auto stageB = [&](int NH, bf16_t* lds, int kt) {
    #pragma unroll
    for (int u = 0; u < 2; ++u) {
      int rowbase = u * 128 + ((wv >> 2) << 6) + NH * 32 + ((wv & 3) << 3);
      int row = rowbase + (lane >> 3);
      int slot = (lane & 7) ^ (row & 7);
      gload_lds16(Bw + (size_t)(bn + row) * Kk + kt * 64 + slot * 8,
                  (char*)lds + rowbase * 128);
    }
  };

  // prologue: full tile 0, hard drain
  stageA(0, As[0], 0); stageA(1, As[0], 0);
  stageB(0, Bs[0], 0); stageB(1, Bs[0], 0);
  asm volatile("s_waitcnt vmcnt(0)" ::: "memory");
  __builtin_amdgcn_s_barrier();
  __builtin_amdgcn_sched_barrier(0);

#define DS_A(AV, MH, KK)                                                         \
    _Pragma("unroll") for (int mi = 0; mi < 4; ++mi) {                           \
      const int row = wm * 128 + (MH) * 64 + mi * 16 + ln15;                     \
      const int slot = (KK) * 4 + ln4;                                           \
      AV[mi] = *(const bf16x8*)(Ab + row * 128 + ((slot ^ (row & 7)) << 4));     \
    }
#define DS_B(KK)                                                                 \
    _Pragma("unroll") for (int nj = 0; nj < 4; ++nj) {                           \
      const int row = wn * 64 + nj * 16 + ln15;                                  \
      const int slot = (KK) * 4 + ln4;                                           \
      bvv[nj] = *(const bf16x8*)(Bb + row * 128 + ((slot ^ (row & 7)) << 4));    \
    }
#define MMA(AV, MH)                                                              \
    __builtin_amdgcn_s_setprio(1);                                               \
    _Pragma("unroll") for (int mi = 0; mi < 4; ++mi)                             \
      _Pragma("unroll") for (int nj = 0; nj < 4; ++nj)                           \
        acc[(MH)*4+mi][nj] = __builtin_amdgcn_mfma_f32_16x16x32_bf16(            \
            AV[mi], bvv[nj], acc[(MH)*4+mi][nj], 0, 0, 0);                       \
    __builtin_amdgcn_s_setprio(0);

  for (int t = 0; t < NT; ++t) {
    const int cur = t & 1;
    const char* Ab = (const char*)As[cur];
    const char* Bb = (const char*)Bs[cur];
    bf16_t* nA = As[cur ^ 1];
    bf16_t* nB = Bs[cur ^ 1];
    const bool more = (t + 1 < NT);
    bf16x8 ae[4], ao[4], bvv[4];

    // front-load reads for clusters 1-2, plus B stages of t+1
    DS_A(ae, 0, 0); DS_B(0); DS_A(ao, 1, 0);
    if (more) { stageB(0, nB, t + 1); stageB(1, nB, t + 1); }
    // cluster 1 (A mh0 x B, k0); reads for cluster 3 + A stages overlap it
    MMA(ae, 0);
    DS_A(ae, 0, 1);
    if (more) { stageA(0, nA, t + 1); stageA(1, nA, t + 1); }
    // cluster 2 (A mh1 x B, k0); reads for cluster 4 (B k1, A mh1 k1) overlap it
    MMA(ao, 1);
    DS_B(1); DS_A(ao, 1, 1);
    // clusters 3 and 4 (k1)
    MMA(ae, 0);
    MMA(ao, 1);
    // tile boundary: own stages drained, then all-wave barrier
    asm volatile("s_waitcnt vmcnt(0)" ::: "memory");
    __builtin_amdgcn_sched_barrier(0);
    __builtin_amdgcn_s_barrier();
    __builtin_amdgcn_sched_barrier(0);
  }
#undef DS_A
#undef DS_B
#undef MMA

  // epilogue: C/D layout col=lane&15, row=(lane>>4)*4+reg
  #pragma unroll
  for (int am = 0; am < 8; ++am) {
    #pragma unroll
    for (int an = 0; an < 4; ++an) {
      #pragma unroll
      for (int rr = 0; rr < 4; ++rr) {
        int row = bm + wm * 128 + am * 16 + (lane >> 4) * 4 + rr;
        int col = bn + wn * 64 + an * 16 + ln15;
        float v = acc[am][an][rr] + bias[col];
        if (RELU) v = fmaxf(v, 0.f);
        outb[(size_t)row * Nn + col] = (bf16_t)v;
      }
    }
  }
}

// ---------------- approx top-8 per row ----------------
__global__ void __launch_bounds__(256)
topk8_k(const float* __restrict__ sim, const double* __restrict__ rnd,
        int* __restrict__ cand)
{
  __shared__ float vals[NN];
  __shared__ float rv[256];
  __shared__ int   ri[256];
  int b = blockIdx.x, tid = threadIdx.x;
  for (int t = 0; t < NN / 256; ++t) {
    int i = tid + t * 256;
    vals[i] = sim[(size_t)b * NN + i] * (float)rnd[i];
  }
  __syncthreads();
  for (int p = 0; p < 8; ++p) {
    float bvv = -INFINITY; int bi = NN;
    for (int t = 0; t < NN / 256; ++t) {
      int i = tid + t * 256;
      float v = vals[i];
      if (v > bvv) { bvv = v; bi = i; }   // strict > keeps lowest index
    }
    rv[tid] = bvv; ri[tid] = bi;
    __syncthreads();
    for (int s = 128; s > 0; s >>= 1) {
      if (tid < s) {
        float v2 = rv[tid + s]; int i2 = ri[tid + s];
        if (v2 > rv[tid] || (v2 == rv[tid] && i2 < ri[tid])) { rv[tid] = v2; ri[tid] = i2; }
      }
      __syncthreads();
    }
    if (tid == 0) {
      int wsel = ri[0];
      cand[b * 8 + p] = wsel;
      vals[wsel] = -INFINITY;
    }
    __syncthreads();
  }
}

// ---------------- fp64 re-rank of the 8 candidates -> exact top-5 ----------------
__global__ void __launch_bounds__(256)
refine_k(const float* __restrict__ m0, const float* __restrict__ s0,
         const double* __restrict__ rnd, const int* __restrict__ cand,
         int* __restrict__ topidx)
{
  __shared__ double red[256];
  __shared__ double vals[8];
  int b = blockIdx.x, tid = threadIdx.x;
  int cs[8];
  #pragma unroll
  for (int j = 0; j < 8; ++j) cs[j] = cand[b * 8 + j];
  const float* q = m0 + (size_t)b * DD;
  double part[8];
  #pragma unroll
  for (int j = 0; j < 8; ++j) part[j] = 0.0;
  for (int d = tid; d < DD; d += 256) {
    double qd = (double)q[d];
    #pragma unroll
    for (int j = 0; j < 8; ++j)
      part[j] += qd * (double)s0[(size_t)cs[j] * DD + d];
  }
  for (int j = 0; j < 8; ++j) {
    red[tid] = part[j]; __syncthreads();
    for (int s = 128; s > 0; s >>= 1) {
      if (tid < s) red[tid] += red[tid + s];
      __syncthreads();
    }
    if (tid == 0) vals[j] = red[0] * rnd[cs[j]];
    __syncthreads();
  }
  if (tid == 0) {
    bool used[8] = {false,false,false,false,false,false,false,false};
    for (int p = 0; p < KSEL; ++p) {
      int best = -1;
      for (int j = 0; j < 8; ++j) {
        if (used[j]) continue;
        if (best < 0 || vals[j] > vals[best] ||
            (vals[j] == vals[best] && cs[j] < cs[best])) best = j;
      }
      used[best] = true;
      topidx[b * KSEL + p] = cs[best];
    }
  }
}

// ---- fused attention over merged eKV rows: ctx[d] = sum_j a_{head(d),j} * eV[idx_j][d] ----
__global__ void __launch_bounds__(256)
attn_k(const bf16_t* __restrict__ q, const bf16_t* __restrict__ eKV,
       const int* __restrict__ tidx,
       bf16_t* __restrict__ ctx, float* __restrict__ attn_out)
{
  __shared__ float aw[NHEAD][KSEL];
  const int b = blockIdx.x, t = threadIdx.x;
  const int d0 = t << 2;                 // 4 dims per thread; head = t>>5
  int idx[KSEL];
  #pragma unroll
  for (int j = 0; j < KSEL; ++j) idx[j] = tidx[b * KSEL + j];

  bf16x4 qv = *(const bf16x4*)(q + (size_t)b * DD + d0);
  float s[KSEL];
  #pragma unroll
  for (int j = 0; j < KSEL; ++j) {
    bf16x4 kv = *(const bf16x4*)(eKV + (size_t)idx[j] * 2048 + d0);
    float p = (float)qv[0] * (float)kv[0] + (float)qv[1] * (float)kv[1]
            + (float)qv[2] * (float)kv[2] + (float)qv[3] * (float)kv[3];
    #pragma unroll
    for (int m = 16; m > 0; m >>= 1) p += __shfl_xor(p, m);  // reduce 32-thread head group
    s[j] = p * 0.08838834764831845f;     // 1/sqrt(128)
  }
  float mx = s[0];
  #pragma unroll
  for (int j = 1; j < KSEL; ++j) mx = fmaxf(mx, s[j]);
  float e[KSEL], sum = 0.f;
  #pragma unroll
  for (int j = 0; j < KSEL; ++j) { e[j] = expf(s[j] - mx); sum += e[j]; }
  float inv = 1.f / sum;

  float c0 = 0.f, c1 = 0.f, c2 = 0.f, c3 = 0.f;
  #pragma unroll
  for (int j = 0; j < KSEL; ++j) {
    float a = e[j] * inv;
    bf16x4 vv = *(const bf16x4*)(eKV + (size_t)idx[j] * 2048 + 1024 + d0);
    c0 += a * (float)vv[0]; c1 += a * (float)vv[1];
    c2 += a * (float)vv[2]; c3 += a * (float)vv[3];
    if ((t & 31) == 0) aw[t >> 5][j] = a;
  }
  bf16x4 co; co[0] = (bf16_t)c0; co[1] = (bf16_t)c1; co[2] = (bf16_t)c2; co[3] = (bf16_t)c3;
  *(bf16x4*)(ctx + (size_t)b * DD + d0) = co;
  __syncthreads();
  if (t < KSEL) {
    float m = 0.f;
    #pragma unroll
    for (int hh = 0; hh < NHEAD; ++hh) m += aw[hh][t];
    attn_out[(size_t)b * KSEL + t] = m * 0.125f;
  }
}

// ---------------- launch ----------------
extern "C" void kernel_launch(void* const* d_in, const int* in_sizes, int n_in,
                              void* d_out, int out_size, void* d_ws, size_t ws_size,
                              hipStream_t stream) {
  (void)in_sizes; (void)n_in; (void)out_size; (void)ws_size;
  const float* morph0 = (const float*)d_in[0];
  const float* s0     = (const float*)d_in[1];
  const float* s1     = (const float*)d_in[2];
  const float* wq = (const float*)d_in[3];  const float* bq = (const float*)d_in[4];
  const float* wk = (const float*)d_in[5];  const float* bk = (const float*)d_in[6];
  const float* wv = (const float*)d_in[7];  const float* bv = (const float*)d_in[8];
  const float* wo = (const float*)d_in[9];  const float* bo = (const float*)d_in[10];
  const float* w1 = (const float*)d_in[11]; const float* b1 = (const float*)d_in[12];
  const float* w2 = (const float*)d_in[13]; const float* b2 = (const float*)d_in[14];
  const float* w3 = (const float*)d_in[15]; const float* b3 = (const float*)d_in[16];

  char* ws = (char*)d_ws;
  size_t off = 0;
  auto alloc = [&](size_t bytes) { char* p = ws + off; off += (bytes + 255) & ~(size_t)255; return p; };

  float*  sim  = (float*) alloc((size_t)BB * NN * 4);     // 33.5MB, reused as h1 (bf16) later
  bf16_t* m0b  = (bf16_t*)alloc((size_t)BB * DD * 2);
  bf16_t* s0b  = (bf16_t*)alloc((size_t)NN * DD * 2);
  bf16_t* evo  = (bf16_t*)alloc((size_t)NN * DD * 2);
  double* rnd  = (double*)alloc((size_t)NN * 8);
  int*    cand = (int*)   alloc((size_t)BB * 8 * 4);
  int*    tidx = (int*)   alloc((size_t)BB * KSEL * 4);
  bf16_t* qb   = (bf16_t*)alloc((size_t)BB * DD * 2);
  bf16_t* eKVb = (bf16_t*)alloc((size_t)NN * 2048 * 2);
  bf16_t* ctxb = (bf16_t*)alloc((size_t)BB * DD * 2);
  bf16_t* xb   = (bf16_t*)alloc((size_t)BB * DD * 2);
  bf16_t* wqb  = (bf16_t*)alloc((size_t)DD * DD * 2);
  bf16_t* wkvb = (bf16_t*)alloc((size_t)2048 * DD * 2);
  bf16_t* wob  = (bf16_t*)alloc((size_t)DD * DD * 2);
  bf16_t* w1b  = (bf16_t*)alloc((size_t)HH * DD * 2);
  bf16_t* w2b  = (bf16_t*)alloc((size_t)HH * HH * 2);
  bf16_t* w3b  = (bf16_t*)alloc((size_t)DD * HH * 2);
  float*  bkv  = (float*) alloc((size_t)2048 * 4);
  bf16_t* h2b  = (bf16_t*)alloc((size_t)BB * HH * 2);
  bf16_t* h1b  = (bf16_t*)sim;  // alias: sim dead after topk; sizes match (33.5MB)
  float*  attn_out = (float*)d_out + (size_t)BB * DD;

  // fused prep: all fp32->bf16 conversions + evo + merged wkv + bkv in one launch
  prep_k<<<dim3(2048), dim3(256), 0, stream>>>(
      (const float4*)morph0, (const float4*)s0, (const float4*)s1,
      (const float4*)wq, (const float4*)wk, (const float4*)wv, (const float4*)wo,
      (const float4*)w1, (const float4*)w2, (const float4*)w3,
      (const float4*)bk, (const float4*)bv,
      (ushort4*)m0b, (ushort4*)s0b, (ushort4*)evo,
      (ushort4*)wqb, (ushort4*)wkvb, (ushort4*)wob,
      (ushort4*)w1b, (ushort4*)w2b, (ushort4*)w3b, (float4*)bkv);
  rnormd_k<<<dim3(NN), dim3(256), 0, stream>>>(s0, rnd);

  // retrieval
  gemm_bt<false,false,false><<<dim3(NN/128, BB/128), dim3(256), 0, stream>>>(
      m0b, s0b, nullptr, nullptr, sim, nullptr, BB, NN, DD);
  topk8_k<<<dim3(BB), dim3(256), 0, stream>>>(sim, rnd, cand);
  refine_k<<<dim3(BB), dim3(256), 0, stream>>>(morph0, s0, rnd, cand, tidx);

  // projections: q on morph0; merged K|V on the 2048 unique evo rows
  gemm_bt<false,false,true><<<dim3(DD/128, BB/128), dim3(256), 0, stream>>>(
      m0b, wqb, bq, nullptr, nullptr, qb, BB, DD, DD);
  gemm_bt<false,false,true><<<dim3(2048/128, NN/128), dim3(256), 0, stream>>>(
      evo, wkvb, bkv, nullptr, nullptr, eKVb, NN, 2048, DD);

  // fused attention: scores, softmax, ctx (per-head weights in value space); attn_weights out
  attn_k<<<dim3(BB), dim3(256), 0, stream>>>(qb, eKVb, tidx, ctxb, attn_out);

  // out-proj + residual -> x
  gemm_bt<false,true,true><<<dim3(DD/128, BB/128), dim3(256), 0, stream>>>(
      ctxb, wob, bo, morph0, nullptr, xb, BB, DD, DD);

  // MLP: big square GEMMs on the interleaved 256^2 kernel
  gemm8p<true><<<dim3((BB/256)*(HH/256)), dim3(512), 0, stream>>>(
      xb, w1b, b1, h1b, HH, DD, HH/256);
  gemm8p<true><<<dim3((BB/256)*(HH/256)), dim3(512), 0, stream>>>(
      h1b, w2b, b2, h2b, HH, HH, HH/256);
  gemm_bt<false,true,false><<<dim3(DD/128, BB/128), dim3(256), 0, stream>>>(
      h2b, w3b, b3, morph0, (float*)d_out, nullptr, BB, DD, HH);
}